// Round 1
// baseline (495.936 us; speedup 1.0000x reference)
//
#include <hip/hip_runtime.h>
#include <hip/hip_bf16.h>
#include <cstdint>
#include <cstddef>

using u16 = unsigned short;
typedef __bf16 bf16x8 __attribute__((ext_vector_type(8)));
typedef float f32x4 __attribute__((ext_vector_type(4)));
typedef u16 u16x4 __attribute__((ext_vector_type(4)));
typedef u16 u16x8 __attribute__((ext_vector_type(8)));

__device__ __forceinline__ u16 f2bf(float f) {
  uint32_t u = __builtin_bit_cast(uint32_t, f);
  u += 0x7FFFu + ((u >> 16) & 1u);   // RNE
  return (u16)(u >> 16);
}

__device__ __forceinline__ void gld_lds16(const void* g, void* l) {
  __builtin_amdgcn_global_load_lds(
      (const __attribute__((address_space(1))) unsigned int*)g,
      (__attribute__((address_space(3))) unsigned int*)l, 16, 0, 0);
}

#define MFMA(a, b, c) __builtin_amdgcn_mfma_f32_16x16x32_bf16((a), (b), (c), 0, 0, 0)

// ---------------- fp32 -> bf16 convert ----------------
__global__ void cvt_kernel(const float* __restrict__ in, u16* __restrict__ out, int n4) {
  int i = blockIdx.x * blockDim.x + threadIdx.x;
  int stride = gridDim.x * blockDim.x;
  for (; i < n4; i += stride) {
    float4 v = reinterpret_cast<const float4*>(in)[i];
    u16x4 o;
    o[0] = f2bf(v.x); o[1] = f2bf(v.y); o[2] = f2bf(v.z); o[3] = f2bf(v.w);
    reinterpret_cast<u16x4*>(out)[i] = o;
  }
}

// ---------------- bf16 GEMM: C[M,N] = A[M,K] @ B[N,K]^T ----------------
// m97 structure: 128x128 tile, BK=32, 4 waves (2x2), each wave 64x64 (4x4 MFMA frags).
template <bool OUT_BF16>
__global__ __launch_bounds__(256) void gemm_bt(const u16* __restrict__ A,
                                               const u16* __restrict__ B,
                                               void* __restrict__ Cv,
                                               int M, int N, int K) {
  __shared__ __align__(16) u16 Ash[128 * 32];
  __shared__ __align__(16) u16 Bsh[128 * 32];
  const int tid = threadIdx.x;
  const int w = tid >> 6, lane = tid & 63, ql = lane & 15, g = lane >> 4;
  const int wr = w >> 1, wc = w & 1;
  const int m0 = blockIdx.y * 128, n0 = blockIdx.x * 128;
  // staging: linear LDS = wave-uniform base + lane*16B (global_load_lds rule)
  const int srow = w * 16 + (lane >> 2);
  const int sk = (lane & 3) * 8;
  const u16* Abase = A + (size_t)(m0 + srow) * K + sk;
  const u16* Bbase = B + (size_t)(n0 + srow) * K + sk;

  f32x4 acc[4][4];
#pragma unroll
  for (int i = 0; i < 4; i++)
#pragma unroll
    for (int j = 0; j < 4; j++) acc[i][j] = f32x4{0.f, 0.f, 0.f, 0.f};

  for (int kt = 0; kt < K; kt += 32) {
    gld_lds16(Abase + kt,                  Ash + w * 512);
    gld_lds16(Abase + (size_t)64 * K + kt, Ash + 2048 + w * 512);
    gld_lds16(Bbase + kt,                  Bsh + w * 512);
    gld_lds16(Bbase + (size_t)64 * K + kt, Bsh + 2048 + w * 512);
    __syncthreads();  // vmcnt drain + barrier: tile visible
    bf16x8 af[4], bfr[4];
#pragma unroll
    for (int i = 0; i < 4; i++)
      af[i] = *reinterpret_cast<const bf16x8*>(&Ash[(wr * 64 + i * 16 + ql) * 32 + g * 8]);
#pragma unroll
    for (int j = 0; j < 4; j++)
      bfr[j] = *reinterpret_cast<const bf16x8*>(&Bsh[(wc * 64 + j * 16 + ql) * 32 + g * 8]);
#pragma unroll
    for (int i = 0; i < 4; i++)
#pragma unroll
      for (int j = 0; j < 4; j++)
        acc[i][j] = MFMA(af[i], bfr[j], acc[i][j]);
    __syncthreads();  // all waves done reading before next stage
  }

#pragma unroll
  for (int i = 0; i < 4; i++)
#pragma unroll
    for (int j = 0; j < 4; j++)
#pragma unroll
      for (int r = 0; r < 4; r++) {
        const int row = m0 + wr * 64 + i * 16 + g * 4 + r;
        const int col = n0 + wc * 64 + j * 16 + ql;
        if constexpr (OUT_BF16)
          ((u16*)Cv)[(size_t)row * N + col] = f2bf(acc[i][j][r]);
        else
          ((float*)Cv)[(size_t)row * N + col] = acc[i][j][r];
      }
}

// ---------------- flash attention ----------------
// QKV: [4096][3072] bf16 (Q cols 0..2047 head-major, K cols 2048..2559, V 2560..3071)
// O:   [4096][2048] bf16, head h at cols h*128..h*128+127
// grid: (32 q-tiles of 64 rows, 32 = b*16+h). block: 256 thr / 4 waves, wave = 16 q rows.
// Swapped form: S^T = mfma(K, Q): lane-local softmax per q-column.
__global__ __launch_bounds__(256) void attn_kernel(const u16* __restrict__ QKV,
                                                   u16* __restrict__ O) {
  const int tid = threadIdx.x, w = tid >> 6, lane = tid & 63;
  const int ql = lane & 15, g = lane >> 4;
  const int qt = blockIdx.x;
  const int b = blockIdx.y >> 4, h = blockIdx.y & 15, hkv = h >> 2;
  const size_t rowb = (size_t)b * 2048;
  const int qbase = qt * 64;

  __shared__ __align__(16) u16 VT[128 * 80];   // V^T tile [d][s], stride 80 (pad)
  __shared__ __align__(16) u16 PW[4 * 16 * 80];// per-wave P^T as P[q][s], stride 80

  // Q B-frags, held in regs entire kernel: col q = ql, k = kk*32 + g*8..+7
  bf16x8 bq[4];
  {
    const u16* qp = QKV + ((rowb + qbase + w * 16 + ql) * 3072 + h * 128 + g * 8);
#pragma unroll
    for (int kk = 0; kk < 4; kk++)
      bq[kk] = *reinterpret_cast<const bf16x8*>(qp + kk * 32);
  }

  f32x4 oacc[8];
#pragma unroll
  for (int dt = 0; dt < 8; dt++) oacc[dt] = f32x4{0.f, 0.f, 0.f, 0.f};
  float m = -INFINITY, l = 0.f;
  const float CEXP = 0.08838834764831845f * 1.4426950408889634f;  // scale*log2e

#pragma unroll 1
  for (int sb = 0; sb < 32; sb++) {
    const int sbase = sb * 64;
    // ---- stage V^T (cooperative transpose-write) ----
    {
      const int s = tid & 63;
      const int dc0 = tid >> 6;
      const u16* vbase = QKV + ((rowb + sbase + s) * 3072 + 2560 + hkv * 128);
#pragma unroll
      for (int c = 0; c < 4; c++) {
        const int dc = dc0 + 4 * c;  // 0..15, d0 = dc*8
        u16x8 v = *reinterpret_cast<const u16x8*>(vbase + dc * 8);
#pragma unroll
        for (int j = 0; j < 8; j++) VT[(dc * 8 + j) * 80 + s] = v[j];
      }
    }
    __syncthreads();

    // ---- S^T = K @ Q^T (A=K rows=s, B=Q cols=q), direct global K reads ----
    f32x4 sc[4];
    const u16* kbase = QKV + ((rowb + sbase + ql) * 3072 + 2048 + hkv * 128 + g * 8);
#pragma unroll
    for (int nt = 0; nt < 4; nt++) {
      f32x4 c = {0.f, 0.f, 0.f, 0.f};
      const u16* kp = kbase + (size_t)nt * 16 * 3072;
#pragma unroll
      for (int kk = 0; kk < 4; kk++) {
        bf16x8 a = *reinterpret_cast<const bf16x8*>(kp + kk * 32);
        c = MFMA(a, bq[kk], c);
      }
      sc[nt] = c;  // lane holds S[s = sbase+nt*16+g*4+r][q = qbase+w*16+ql]
    }

    // ---- online softmax (per q-column = per lane, reduce across g via shfl) ----
    float tmax = -INFINITY;
#pragma unroll
    for (int nt = 0; nt < 4; nt++)
#pragma unroll
      for (int r = 0; r < 4; r++) tmax = fmaxf(tmax, sc[nt][r]);
    tmax = fmaxf(tmax, __shfl_xor(tmax, 16));
    tmax = fmaxf(tmax, __shfl_xor(tmax, 32));
    const float mnew = fmaxf(m, tmax);
    const float corr = exp2f((m - mnew) * CEXP);
    float ps = 0.f;
#pragma unroll
    for (int nt = 0; nt < 4; nt++) {
      u16x4 pkv;
#pragma unroll
      for (int r = 0; r < 4; r++) {
        float p = exp2f((sc[nt][r] - mnew) * CEXP);
        ps += p;
        pkv[r] = f2bf(p);
      }
      // P[q][s]: s = nt*16 + g*4 + r  (b64 write)
      *reinterpret_cast<u16x4*>(&PW[w * 1280 + ql * 80 + nt * 16 + g * 4]) = pkv;
    }
    ps += __shfl_xor(ps, 16);
    ps += __shfl_xor(ps, 32);
    l = l * corr + ps;
    m = mnew;
#pragma unroll
    for (int dt = 0; dt < 8; dt++) oacc[dt] = oacc[dt] * corr;

    // ---- O^T += V^T @ P^T ----
    bf16x8 bp0 = *reinterpret_cast<const bf16x8*>(&PW[w * 1280 + ql * 80 + g * 8]);
    bf16x8 bp1 = *reinterpret_cast<const bf16x8*>(&PW[w * 1280 + ql * 80 + 32 + g * 8]);
#pragma unroll
    for (int dt = 0; dt < 8; dt++) {
      bf16x8 av0 = *reinterpret_cast<const bf16x8*>(&VT[(dt * 16 + ql) * 80 + g * 8]);
      bf16x8 av1 = *reinterpret_cast<const bf16x8*>(&VT[(dt * 16 + ql) * 80 + 32 + g * 8]);
      oacc[dt] = MFMA(av0, bp0, oacc[dt]);
      oacc[dt] = MFMA(av1, bp1, oacc[dt]);
    }
    __syncthreads();  // all reads done before next V^T stage
  }

  // ---- epilogue: normalize, transpose via LDS (reuse VT), coalesced store ----
  const float rl = 1.0f / l;
  u16* ol = VT + w * 2176;  // per-wave [16 q][136] bf16
#pragma unroll
  for (int dt = 0; dt < 8; dt++) {
    u16x4 pv;
#pragma unroll
    for (int r = 0; r < 4; r++) pv[r] = f2bf(oacc[dt][r] * rl);
    *reinterpret_cast<u16x4*>(ol + ql * 136 + dt * 16 + g * 4) = pv;  // O[q][d..d+3]
  }
  const int qr = lane >> 2, c4 = lane & 3;
  u16* op = O + ((rowb + qbase + w * 16 + qr) * 2048 + h * 128 + c4 * 32);
#pragma unroll
  for (int j = 0; j < 4; j++) {
    u16x8 v = *reinterpret_cast<const u16x8*>(ol + qr * 136 + c4 * 32 + j * 8);
    *reinterpret_cast<u16x8*>(op + j * 8) = v;
  }
}

// ---------------- launch ----------------
extern "C" void kernel_launch(void* const* d_in, const int* in_sizes, int n_in,
                              void* d_out, int out_size, void* d_ws, size_t ws_size,
                              hipStream_t stream) {
  (void)in_sizes; (void)n_in; (void)out_size;
  const float* x  = (const float*)d_in[0];
  const float* Wq = (const float*)d_in[1];
  const float* Wk = (const float*)d_in[2];
  const float* Wv = (const float*)d_in[3];
  const float* Wo = (const float*)d_in[4];

  // ws layout (bf16 elems): xb 8388608 | Wc 6291456 | QKV 12582912  => ~54.5 MB
  if (ws_size < (size_t)(8388608 + 6291456 + 12582912) * 2) return;
  u16* xb  = (u16*)d_ws;
  u16* Wc  = xb + 8388608;
  u16* QKV = Wc + 6291456;
  u16* Ob  = xb;  // reuse x-bf16 region for attention output (x no longer needed)

  cvt_kernel<<<2048, 256, 0, stream>>>(x,  xb, 2097152);
  cvt_kernel<<<2048, 256, 0, stream>>>(Wq, Wc, 1048576);
  cvt_kernel<<<1024, 256, 0, stream>>>(Wk, Wc + 4194304, 262144);
  cvt_kernel<<<1024, 256, 0, stream>>>(Wv, Wc + 5242880, 262144);
  // QKV = x @ [Wq;Wk;Wv]^T
  gemm_bt<true><<<dim3(24, 32), 256, 0, stream>>>(xb, Wc, (void*)QKV, 4096, 3072, 2048);
  // reuse Wc region for Wo (stream-ordered after GEMM1)
  cvt_kernel<<<2048, 256, 0, stream>>>(Wo, Wc, 1048576);
  attn_kernel<<<dim3(32, 32), 256, 0, stream>>>(QKV, Ob);
  // out = O @ Wo^T (fp32 out)
  gemm_bt<false><<<dim3(16, 32), 256, 0, stream>>>(Ob, Wc, d_out, 4096, 2048, 2048);
}

// Round 2
// 490.703 us; speedup vs baseline: 1.0107x; 1.0107x over previous
//
#include <hip/hip_runtime.h>
#include <hip/hip_bf16.h>
#include <cstdint>
#include <cstddef>

using u16 = unsigned short;
typedef __bf16 bf16x8 __attribute__((ext_vector_type(8)));
typedef float f32x4 __attribute__((ext_vector_type(4)));
typedef u16 u16x4 __attribute__((ext_vector_type(4)));
typedef u16 u16x8 __attribute__((ext_vector_type(8)));

__device__ __forceinline__ u16 f2bf(float f) {
  uint32_t u = __builtin_bit_cast(uint32_t, f);
  u += 0x7FFFu + ((u >> 16) & 1u);   // RNE
  return (u16)(u >> 16);
}

__device__ __forceinline__ void gld_lds16(const void* g, void* l) {
  __builtin_amdgcn_global_load_lds(
      (const __attribute__((address_space(1))) unsigned int*)g,
      (__attribute__((address_space(3))) unsigned int*)l, 16, 0, 0);
}

#define MFMA(a, b, c) __builtin_amdgcn_mfma_f32_16x16x32_bf16((a), (b), (c), 0, 0, 0)

// ---------------- fp32 -> bf16 convert ----------------
__global__ void cvt_kernel(const float* __restrict__ in, u16* __restrict__ out, int n4) {
  int i = blockIdx.x * blockDim.x + threadIdx.x;
  int stride = gridDim.x * blockDim.x;
  for (; i < n4; i += stride) {
    float4 v = reinterpret_cast<const float4*>(in)[i];
    u16x4 o;
    o[0] = f2bf(v.x); o[1] = f2bf(v.y); o[2] = f2bf(v.z); o[3] = f2bf(v.w);
    reinterpret_cast<u16x4*>(out)[i] = o;
  }
}

// ---------------- bf16 GEMM: C[M,N] = A[M,K] @ B[N,K]^T (m97 structure) ----------------
template <bool OUT_BF16>
__global__ __launch_bounds__(256) void gemm_bt(const u16* __restrict__ A,
                                               const u16* __restrict__ B,
                                               void* __restrict__ Cv,
                                               int M, int N, int K) {
  __shared__ __align__(16) u16 Ash[128 * 32];
  __shared__ __align__(16) u16 Bsh[128 * 32];
  const int tid = threadIdx.x;
  const int w = tid >> 6, lane = tid & 63, ql = lane & 15, g = lane >> 4;
  const int wr = w >> 1, wc = w & 1;
  const int m0 = blockIdx.y * 128, n0 = blockIdx.x * 128;
  const int srow = w * 16 + (lane >> 2);
  const int sk = (lane & 3) * 8;
  const u16* Abase = A + (size_t)(m0 + srow) * K + sk;
  const u16* Bbase = B + (size_t)(n0 + srow) * K + sk;

  f32x4 acc[4][4];
#pragma unroll
  for (int i = 0; i < 4; i++)
#pragma unroll
    for (int j = 0; j < 4; j++) acc[i][j] = f32x4{0.f, 0.f, 0.f, 0.f};

  for (int kt = 0; kt < K; kt += 32) {
    gld_lds16(Abase + kt,                  Ash + w * 512);
    gld_lds16(Abase + (size_t)64 * K + kt, Ash + 2048 + w * 512);
    gld_lds16(Bbase + kt,                  Bsh + w * 512);
    gld_lds16(Bbase + (size_t)64 * K + kt, Bsh + 2048 + w * 512);
    __syncthreads();
    bf16x8 af[4], bfr[4];
#pragma unroll
    for (int i = 0; i < 4; i++)
      af[i] = *reinterpret_cast<const bf16x8*>(&Ash[(wr * 64 + i * 16 + ql) * 32 + g * 8]);
#pragma unroll
    for (int j = 0; j < 4; j++)
      bfr[j] = *reinterpret_cast<const bf16x8*>(&Bsh[(wc * 64 + j * 16 + ql) * 32 + g * 8]);
#pragma unroll
    for (int i = 0; i < 4; i++)
#pragma unroll
      for (int j = 0; j < 4; j++)
        acc[i][j] = MFMA(af[i], bfr[j], acc[i][j]);
    __syncthreads();
  }

#pragma unroll
  for (int i = 0; i < 4; i++)
#pragma unroll
    for (int j = 0; j < 4; j++)
#pragma unroll
      for (int r = 0; r < 4; r++) {
        const int row = m0 + wr * 64 + i * 16 + g * 4 + r;
        const int col = n0 + wc * 64 + j * 16 + ql;
        if constexpr (OUT_BF16)
          ((u16*)Cv)[(size_t)row * N + col] = f2bf(acc[i][j][r]);
        else
          ((float*)Cv)[(size_t)row * N + col] = acc[i][j][r];
      }
}

// ---------------- flash attention v2 ----------------
// QKV: [4096][3072] bf16 (Q 0..2047, K 2048..2559, V 2560..3071); O: [4096][2048].
// grid (16 q-tiles of 128, 32 bh). Block 256 thr / 4 waves; wave owns 32 q (2 halves).
// KVBLK=32, double-buffered K (gld_lds, swizzled) + V^T (reg-staged, swizzled),
// one barrier per iter, T14 issue-early/write-late, T5 setprio.
__global__ __launch_bounds__(256, 2) void attn_kernel(const u16* __restrict__ QKV,
                                                      u16* __restrict__ O) {
  __shared__ __align__(16) u16 Kb[2][32 * 128];   // [s][128d] swizzled: col^=(s&7)<<3 (u16)
  __shared__ __align__(16) u16 Vb[2][128 * 32];   // V^T [d][32s] swizzled: col^=key(d)<<3
  __shared__ __align__(16) u16 PWb[4][2][16 * 40];// per wave/qh: P[q][s], stride 40
  const int tid = threadIdx.x, w = tid >> 6, lane = tid & 63;
  const int ql = lane & 15, g = lane >> 4;
  const int qt = blockIdx.x;
  const int b = blockIdx.y >> 4, h = blockIdx.y & 15, hkv = h >> 2;
  const size_t rowb = (size_t)b * 2048;
  const int qbase = qt * 128;

  // Q fragments held all kernel: col q = ql, k = kk*32 + g*8..+7
  bf16x8 bq[2][4];
#pragma unroll
  for (int qh = 0; qh < 2; qh++) {
    const u16* qp = QKV + ((rowb + qbase + w * 32 + qh * 16 + ql) * 3072 + h * 128 + g * 8);
#pragma unroll
    for (int kk = 0; kk < 4; kk++)
      bq[qh][kk] = *reinterpret_cast<const bf16x8*>(qp + kk * 32);
  }

  // K staging indices: pass p covers LDS u16 [p*2048 + w*512 + lane*8, +8)
  const int ko16 = w * 512 + lane * 8;
  const int ks0 = ko16 >> 7;            // row for pass 0 (pass1: +16)
  const int kcol = ko16 & 127;
  // V load mapping: thread -> (s=sl, d0=dg*16)
  const int dg = tid & 7, sl = tid >> 3;

  const u16* Kg = QKV + 2048 + hkv * 128;
  const u16* Vg = QKV + 2560 + hkv * 128;

  f32x4 oacc[2][8];
#pragma unroll
  for (int qh = 0; qh < 2; qh++)
#pragma unroll
    for (int dt = 0; dt < 8; dt++) oacc[qh][dt] = f32x4{0.f, 0.f, 0.f, 0.f};
  float m[2] = {-INFINITY, -INFINITY}, l[2] = {0.f, 0.f};
  const float CEXP = 0.08838834764831845f * 1.4426950408889634f;  // scale*log2e

  auto stageK = [&](int pb, int sbase) {
#pragma unroll
    for (int p = 0; p < 2; p++) {
      const int s = ks0 + p * 16;
      const u16* src = Kg + (rowb + sbase + s) * 3072 + (kcol ^ ((s & 7) << 3));
      gld_lds16(src, &Kb[pb][p * 2048 + w * 512]);
    }
  };
  auto writeV = [&](int pb, u16x8 v0, u16x8 v1) {
#pragma unroll
    for (int half = 0; half < 2; half++) {
      u16x8 v = half ? v1 : v0;
#pragma unroll
      for (int j = 0; j < 8; j++) {
        const int d = dg * 16 + half * 8 + j;
        const int key = ((d >> 1) ^ (d >> 4)) & 3;
        Vb[pb][d * 32 + (sl ^ (key << 3))] = v[j];
      }
    }
  };

  // ---- prologue: stage tile 0 ----
  u16x8 vr0, vr1;
  {
    const u16* vp = Vg + (rowb + sl) * 3072 + dg * 16;
    vr0 = *reinterpret_cast<const u16x8*>(vp);
    vr1 = *reinterpret_cast<const u16x8*>(vp + 8);
  }
  stageK(0, 0);
  writeV(0, vr0, vr1);
  __syncthreads();

#pragma unroll 1
  for (int sb = 0; sb < 64; sb++) {
    const int pb = sb & 1;
    // T14: issue next-tile loads first (consumed after PV)
    if (sb < 63) {
      const u16* vp = Vg + (rowb + (sb + 1) * 32 + sl) * 3072 + dg * 16;
      vr0 = *reinterpret_cast<const u16x8*>(vp);
      vr1 = *reinterpret_cast<const u16x8*>(vp + 8);
      stageK(pb ^ 1, (sb + 1) * 32);
    }

    // ---- S^T = K @ Q^T ----
    f32x4 sc[2][2];
#pragma unroll
    for (int qh = 0; qh < 2; qh++)
#pragma unroll
      for (int nt = 0; nt < 2; nt++) sc[qh][nt] = f32x4{0.f, 0.f, 0.f, 0.f};
    __builtin_amdgcn_s_setprio(1);
#pragma unroll
    for (int nt = 0; nt < 2; nt++)
#pragma unroll
      for (int kk = 0; kk < 4; kk++) {
        bf16x8 kf = *reinterpret_cast<const bf16x8*>(
            &Kb[pb][(nt * 16 + ql) * 128 + ((kk * 32 + g * 8) ^ ((ql & 7) << 3))]);
        sc[0][nt] = MFMA(kf, bq[0][kk], sc[0][nt]);
        sc[1][nt] = MFMA(kf, bq[1][kk], sc[1][nt]);
      }
    __builtin_amdgcn_s_setprio(0);

    // ---- online softmax per q-half (lane-local per q-col, reduce over g) ----
    float corr[2];
#pragma unroll
    for (int qh = 0; qh < 2; qh++) {
      float tmax = -INFINITY;
#pragma unroll
      for (int nt = 0; nt < 2; nt++)
#pragma unroll
        for (int r = 0; r < 4; r++) tmax = fmaxf(tmax, sc[qh][nt][r]);
      tmax = fmaxf(tmax, __shfl_xor(tmax, 16));
      tmax = fmaxf(tmax, __shfl_xor(tmax, 32));
      const float mnew = fmaxf(m[qh], tmax);
      corr[qh] = exp2f((m[qh] - mnew) * CEXP);
      float ps = 0.f;
#pragma unroll
      for (int nt = 0; nt < 2; nt++) {
        u16x4 pk;
#pragma unroll
        for (int r = 0; r < 4; r++) {
          float p = exp2f((sc[qh][nt][r] - mnew) * CEXP);
          ps += p; pk[r] = f2bf(p);
        }
        *reinterpret_cast<u16x4*>(&PWb[w][qh][ql * 40 + nt * 16 + g * 4]) = pk;
      }
      ps += __shfl_xor(ps, 16);
      ps += __shfl_xor(ps, 32);
      l[qh] = l[qh] * corr[qh] + ps;
      m[qh] = mnew;
    }
#pragma unroll
    for (int qh = 0; qh < 2; qh++)
#pragma unroll
      for (int dt = 0; dt < 8; dt++) oacc[qh][dt] *= corr[qh];

    // ---- O^T += V^T @ P^T ----
    bf16x8 bp[2];
#pragma unroll
    for (int qh = 0; qh < 2; qh++)
      bp[qh] = *reinterpret_cast<const bf16x8*>(&PWb[w][qh][ql * 40 + g * 8]);
    __builtin_amdgcn_s_setprio(1);
#pragma unroll
    for (int dt = 0; dt < 8; dt++) {
      const int d = dt * 16 + ql;
      const int key = ((d >> 1) ^ (d >> 4)) & 3;
      bf16x8 av = *reinterpret_cast<const bf16x8*>(&Vb[pb][d * 32 + ((g * 8) ^ (key << 3))]);
      oacc[0][dt] = MFMA(av, bp[0], oacc[0][dt]);
      oacc[1][dt] = MFMA(av, bp[1], oacc[1][dt]);
    }
    __builtin_amdgcn_s_setprio(0);

    if (sb < 63) writeV(pb ^ 1, vr0, vr1);  // write-late: V regs waited here
    __syncthreads();  // compiler drains vmcnt (K gld_lds) + lgkm before barrier
  }

  // ---- epilogue: normalize + LDS transpose for coalesced b128 stores ----
  u16* ol = (w < 2) ? (&Kb[0][0] + w * 2176) : (&Vb[0][0] + (w - 2) * 2176);
#pragma unroll 1
  for (int qh = 0; qh < 2; qh++) {
    const float rl = 1.0f / l[qh];
#pragma unroll
    for (int dt = 0; dt < 8; dt++) {
      u16x4 pv;
#pragma unroll
      for (int r = 0; r < 4; r++) pv[r] = f2bf(oacc[qh][dt][r] * rl);
      *reinterpret_cast<u16x4*>(ol + ql * 136 + dt * 16 + g * 4) = pv;  // O[q][d..d+3]
    }
    const int qr = lane >> 2, c4 = lane & 3;
    u16* op = O + ((rowb + qbase + w * 32 + qh * 16 + qr) * 2048 + h * 128 + c4 * 32);
#pragma unroll
    for (int j = 0; j < 4; j++) {
      u16x8 v = *reinterpret_cast<const u16x8*>(ol + qr * 136 + c4 * 32 + j * 8);
      *reinterpret_cast<u16x8*>(op + j * 8) = v;
    }
    __syncthreads();
  }
}

// ---------------- launch ----------------
extern "C" void kernel_launch(void* const* d_in, const int* in_sizes, int n_in,
                              void* d_out, int out_size, void* d_ws, size_t ws_size,
                              hipStream_t stream) {
  (void)in_sizes; (void)n_in; (void)out_size;
  const float* x  = (const float*)d_in[0];
  const float* Wq = (const float*)d_in[1];
  const float* Wk = (const float*)d_in[2];
  const float* Wv = (const float*)d_in[3];
  const float* Wo = (const float*)d_in[4];

  if (ws_size < (size_t)(8388608 + 6291456 + 12582912) * 2) return;
  u16* xb  = (u16*)d_ws;
  u16* Wc  = xb + 8388608;
  u16* QKV = Wc + 6291456;
  u16* Ob  = xb;  // reuse x-bf16 region for attention output

  cvt_kernel<<<2048, 256, 0, stream>>>(x,  xb, 2097152);
  cvt_kernel<<<2048, 256, 0, stream>>>(Wq, Wc, 1048576);
  cvt_kernel<<<1024, 256, 0, stream>>>(Wk, Wc + 4194304, 262144);
  cvt_kernel<<<1024, 256, 0, stream>>>(Wv, Wc + 5242880, 262144);
  gemm_bt<true><<<dim3(24, 32), 256, 0, stream>>>(xb, Wc, (void*)QKV, 4096, 3072, 2048);
  cvt_kernel<<<2048, 256, 0, stream>>>(Wo, Wc, 1048576);
  attn_kernel<<<dim3(16, 32), 256, 0, stream>>>(QKV, Ob);
  gemm_bt<false><<<dim3(16, 32), 256, 0, stream>>>(Ob, Wc, d_out, 4096, 2048, 2048);
}

// Round 3
// 293.172 us; speedup vs baseline: 1.6916x; 1.6738x over previous
//
#include <hip/hip_runtime.h>
#include <hip/hip_bf16.h>
#include <cstdint>
#include <cstddef>

using u16 = unsigned short;
typedef __bf16 bf16x8 __attribute__((ext_vector_type(8)));
typedef float f32x4 __attribute__((ext_vector_type(4)));
typedef u16 u16x4 __attribute__((ext_vector_type(4)));
typedef u16 u16x8 __attribute__((ext_vector_type(8)));

__device__ __forceinline__ u16 f2bf(float f) {
  uint32_t u = __builtin_bit_cast(uint32_t, f);
  u += 0x7FFFu + ((u >> 16) & 1u);   // RNE
  return (u16)(u >> 16);
}

__device__ __forceinline__ void gld_lds16(const void* g, void* l) {
  __builtin_amdgcn_global_load_lds(
      (const __attribute__((address_space(1))) unsigned int*)g,
      (__attribute__((address_space(3))) unsigned int*)l, 16, 0, 0);
}

#define MFMA(a, b, c) __builtin_amdgcn_mfma_f32_16x16x32_bf16((a), (b), (c), 0, 0, 0)

// ---------------- fp32 -> bf16 convert ----------------
__global__ void cvt_kernel(const float* __restrict__ in, u16* __restrict__ out, int n4) {
  int i = blockIdx.x * blockDim.x + threadIdx.x;
  int stride = gridDim.x * blockDim.x;
  for (; i < n4; i += stride) {
    float4 v = reinterpret_cast<const float4*>(in)[i];
    u16x4 o;
    o[0] = f2bf(v.x); o[1] = f2bf(v.y); o[2] = f2bf(v.z); o[3] = f2bf(v.w);
    reinterpret_cast<u16x4*>(out)[i] = o;
  }
}

// ---------------- bf16 GEMM: C[M,N] = A[M,K] @ B[N,K]^T (m97 structure) ----------------
template <bool OUT_BF16>
__global__ __launch_bounds__(256) void gemm_bt(const u16* __restrict__ A,
                                               const u16* __restrict__ B,
                                               void* __restrict__ Cv,
                                               int M, int N, int K) {
  __shared__ __align__(16) u16 Ash[128 * 32];
  __shared__ __align__(16) u16 Bsh[128 * 32];
  const int tid = threadIdx.x;
  const int w = tid >> 6, lane = tid & 63, ql = lane & 15, g = lane >> 4;
  const int wr = w >> 1, wc = w & 1;
  const int m0 = blockIdx.y * 128, n0 = blockIdx.x * 128;
  const int srow = w * 16 + (lane >> 2);
  const int sk = (lane & 3) * 8;
  const u16* Abase = A + (size_t)(m0 + srow) * K + sk;
  const u16* Bbase = B + (size_t)(n0 + srow) * K + sk;

  f32x4 acc[4][4];
#pragma unroll
  for (int i = 0; i < 4; i++)
#pragma unroll
    for (int j = 0; j < 4; j++) acc[i][j] = f32x4{0.f, 0.f, 0.f, 0.f};

  for (int kt = 0; kt < K; kt += 32) {
    gld_lds16(Abase + kt,                  Ash + w * 512);
    gld_lds16(Abase + (size_t)64 * K + kt, Ash + 2048 + w * 512);
    gld_lds16(Bbase + kt,                  Bsh + w * 512);
    gld_lds16(Bbase + (size_t)64 * K + kt, Bsh + 2048 + w * 512);
    __syncthreads();
    bf16x8 af[4], bfr[4];
#pragma unroll
    for (int i = 0; i < 4; i++)
      af[i] = *reinterpret_cast<const bf16x8*>(&Ash[(wr * 64 + i * 16 + ql) * 32 + g * 8]);
#pragma unroll
    for (int j = 0; j < 4; j++)
      bfr[j] = *reinterpret_cast<const bf16x8*>(&Bsh[(wc * 64 + j * 16 + ql) * 32 + g * 8]);
#pragma unroll
    for (int i = 0; i < 4; i++)
#pragma unroll
      for (int j = 0; j < 4; j++)
        acc[i][j] = MFMA(af[i], bfr[j], acc[i][j]);
    __syncthreads();
  }

#pragma unroll
  for (int i = 0; i < 4; i++)
#pragma unroll
    for (int j = 0; j < 4; j++)
#pragma unroll
      for (int r = 0; r < 4; r++) {
        const int row = m0 + wr * 64 + i * 16 + g * 4 + r;
        const int col = n0 + wc * 64 + j * 16 + ql;
        if constexpr (OUT_BF16)
          ((u16*)Cv)[(size_t)row * N + col] = f2bf(acc[i][j][r]);
        else
          ((float*)Cv)[(size_t)row * N + col] = acc[i][j][r];
      }
}

// ---------------- flash attention v3 ----------------
// Same structure as v2; epilogue statically indexed (rule #20 fix: no runtime
// qh index into oacc/l -> accumulators stay in registers, not scratch).
__global__ __launch_bounds__(256, 2) void attn_kernel(const u16* __restrict__ QKV,
                                                      u16* __restrict__ O) {
  __shared__ __align__(16) u16 Kb[2][32 * 128];   // [s][128d] swizzled: col^=(s&7)<<3 (u16)
  __shared__ __align__(16) u16 Vb[2][128 * 32];   // V^T [d][32s] swizzled: col^=key(d)<<3
  __shared__ __align__(16) u16 PWb[4][2][16 * 40];// per wave/qh: P[q][s], stride 40
  const int tid = threadIdx.x, w = tid >> 6, lane = tid & 63;
  const int ql = lane & 15, g = lane >> 4;
  const int qt = blockIdx.x;
  const int b = blockIdx.y >> 4, h = blockIdx.y & 15, hkv = h >> 2;
  const size_t rowb = (size_t)b * 2048;
  const int qbase = qt * 128;

  // Q fragments held all kernel: col q = ql, k = kk*32 + g*8..+7
  bf16x8 bq[2][4];
#pragma unroll
  for (int qh = 0; qh < 2; qh++) {
    const u16* qp = QKV + ((rowb + qbase + w * 32 + qh * 16 + ql) * 3072 + h * 128 + g * 8);
#pragma unroll
    for (int kk = 0; kk < 4; kk++)
      bq[qh][kk] = *reinterpret_cast<const bf16x8*>(qp + kk * 32);
  }

  const int ko16 = w * 512 + lane * 8;
  const int ks0 = ko16 >> 7;
  const int kcol = ko16 & 127;
  const int dg = tid & 7, sl = tid >> 3;

  const u16* Kg = QKV + 2048 + hkv * 128;
  const u16* Vg = QKV + 2560 + hkv * 128;

  f32x4 oacc[2][8];
#pragma unroll
  for (int qh = 0; qh < 2; qh++)
#pragma unroll
    for (int dt = 0; dt < 8; dt++) oacc[qh][dt] = f32x4{0.f, 0.f, 0.f, 0.f};
  float m[2] = {-INFINITY, -INFINITY}, l[2] = {0.f, 0.f};
  const float CEXP = 0.08838834764831845f * 1.4426950408889634f;  // scale*log2e

  auto stageK = [&](int pb, int sbase) {
#pragma unroll
    for (int p = 0; p < 2; p++) {
      const int s = ks0 + p * 16;
      const u16* src = Kg + (rowb + sbase + s) * 3072 + (kcol ^ ((s & 7) << 3));
      gld_lds16(src, &Kb[pb][p * 2048 + w * 512]);
    }
  };
  auto writeV = [&](int pb, u16x8 v0, u16x8 v1) {
#pragma unroll
    for (int half = 0; half < 2; half++) {
      u16x8 v = half ? v1 : v0;
#pragma unroll
      for (int j = 0; j < 8; j++) {
        const int d = dg * 16 + half * 8 + j;
        const int key = ((d >> 1) ^ (d >> 4)) & 3;
        Vb[pb][d * 32 + (sl ^ (key << 3))] = v[j];
      }
    }
  };

  // ---- prologue: stage tile 0 ----
  u16x8 vr0, vr1;
  {
    const u16* vp = Vg + (rowb + sl) * 3072 + dg * 16;
    vr0 = *reinterpret_cast<const u16x8*>(vp);
    vr1 = *reinterpret_cast<const u16x8*>(vp + 8);
  }
  stageK(0, 0);
  writeV(0, vr0, vr1);
  __syncthreads();

#pragma unroll 1
  for (int sb = 0; sb < 64; sb++) {
    const int pb = sb & 1;
    // T14: issue next-tile loads first (consumed after PV)
    if (sb < 63) {
      const u16* vp = Vg + (rowb + (sb + 1) * 32 + sl) * 3072 + dg * 16;
      vr0 = *reinterpret_cast<const u16x8*>(vp);
      vr1 = *reinterpret_cast<const u16x8*>(vp + 8);
      stageK(pb ^ 1, (sb + 1) * 32);
    }

    // ---- S^T = K @ Q^T ----
    f32x4 sc[2][2];
#pragma unroll
    for (int qh = 0; qh < 2; qh++)
#pragma unroll
      for (int nt = 0; nt < 2; nt++) sc[qh][nt] = f32x4{0.f, 0.f, 0.f, 0.f};
    __builtin_amdgcn_s_setprio(1);
#pragma unroll
    for (int nt = 0; nt < 2; nt++)
#pragma unroll
      for (int kk = 0; kk < 4; kk++) {
        bf16x8 kf = *reinterpret_cast<const bf16x8*>(
            &Kb[pb][(nt * 16 + ql) * 128 + ((kk * 32 + g * 8) ^ ((ql & 7) << 3))]);
        sc[0][nt] = MFMA(kf, bq[0][kk], sc[0][nt]);
        sc[1][nt] = MFMA(kf, bq[1][kk], sc[1][nt]);
      }
    __builtin_amdgcn_s_setprio(0);

    // ---- online softmax per q-half (lane-local per q-col, reduce over g) ----
    float corr[2];
#pragma unroll
    for (int qh = 0; qh < 2; qh++) {
      float tmax = -INFINITY;
#pragma unroll
      for (int nt = 0; nt < 2; nt++)
#pragma unroll
        for (int r = 0; r < 4; r++) tmax = fmaxf(tmax, sc[qh][nt][r]);
      tmax = fmaxf(tmax, __shfl_xor(tmax, 16));
      tmax = fmaxf(tmax, __shfl_xor(tmax, 32));
      const float mnew = fmaxf(m[qh], tmax);
      corr[qh] = exp2f((m[qh] - mnew) * CEXP);
      float ps = 0.f;
#pragma unroll
      for (int nt = 0; nt < 2; nt++) {
        u16x4 pk;
#pragma unroll
        for (int r = 0; r < 4; r++) {
          float p = exp2f((sc[qh][nt][r] - mnew) * CEXP);
          ps += p; pk[r] = f2bf(p);
        }
        *reinterpret_cast<u16x4*>(&PWb[w][qh][ql * 40 + nt * 16 + g * 4]) = pk;
      }
      ps += __shfl_xor(ps, 16);
      ps += __shfl_xor(ps, 32);
      l[qh] = l[qh] * corr[qh] + ps;
      m[qh] = mnew;
    }
#pragma unroll
    for (int qh = 0; qh < 2; qh++)
#pragma unroll
      for (int dt = 0; dt < 8; dt++) oacc[qh][dt] *= corr[qh];

    // ---- O^T += V^T @ P^T ----
    bf16x8 bp[2];
#pragma unroll
    for (int qh = 0; qh < 2; qh++)
      bp[qh] = *reinterpret_cast<const bf16x8*>(&PWb[w][qh][ql * 40 + g * 8]);
    __builtin_amdgcn_s_setprio(1);
#pragma unroll
    for (int dt = 0; dt < 8; dt++) {
      const int d = dt * 16 + ql;
      const int key = ((d >> 1) ^ (d >> 4)) & 3;
      bf16x8 av = *reinterpret_cast<const bf16x8*>(&Vb[pb][d * 32 + ((g * 8) ^ (key << 3))]);
      oacc[0][dt] = MFMA(av, bp[0], oacc[0][dt]);
      oacc[1][dt] = MFMA(av, bp[1], oacc[1][dt]);
    }
    __builtin_amdgcn_s_setprio(0);

    if (sb < 63) writeV(pb ^ 1, vr0, vr1);  // write-late: V regs waited here
    __syncthreads();
  }

  // ---- epilogue: STATIC qh indexing (rule #20: no runtime index into oacc) ----
  u16* ol = (w < 2) ? (&Kb[0][0] + w * 2176) : (&Vb[0][0] + (w - 2) * 2176);
  const int qr = lane >> 2, c4 = lane & 3;
#define ATTN_EPILOGUE(QH)                                                              \
  do {                                                                                 \
    const float rl = 1.0f / l[QH];                                                     \
    _Pragma("unroll")                                                                  \
    for (int dt = 0; dt < 8; dt++) {                                                   \
      u16x4 pv;                                                                        \
      _Pragma("unroll")                                                                \
      for (int r = 0; r < 4; r++) pv[r] = f2bf(oacc[QH][dt][r] * rl);                  \
      *reinterpret_cast<u16x4*>(ol + ql * 136 + dt * 16 + g * 4) = pv;                 \
    }                                                                                  \
    u16* op = O + ((rowb + qbase + w * 32 + (QH) * 16 + qr) * 2048 + h * 128 + c4 * 32);\
    _Pragma("unroll")                                                                  \
    for (int j = 0; j < 4; j++) {                                                      \
      u16x8 v = *reinterpret_cast<const u16x8*>(ol + qr * 136 + c4 * 32 + j * 8);      \
      *reinterpret_cast<u16x8*>(op + j * 8) = v;                                       \
    }                                                                                  \
  } while (0)
  ATTN_EPILOGUE(0);
  ATTN_EPILOGUE(1);
#undef ATTN_EPILOGUE
}

// ---------------- launch ----------------
extern "C" void kernel_launch(void* const* d_in, const int* in_sizes, int n_in,
                              void* d_out, int out_size, void* d_ws, size_t ws_size,
                              hipStream_t stream) {
  (void)in_sizes; (void)n_in; (void)out_size;
  const float* x  = (const float*)d_in[0];
  const float* Wq = (const float*)d_in[1];
  const float* Wk = (const float*)d_in[2];
  const float* Wv = (const float*)d_in[3];
  const float* Wo = (const float*)d_in[4];

  if (ws_size < (size_t)(8388608 + 6291456 + 12582912) * 2) return;
  u16* xb  = (u16*)d_ws;
  u16* Wc  = xb + 8388608;
  u16* QKV = Wc + 6291456;
  u16* Ob  = xb;  // reuse x-bf16 region for attention output

  cvt_kernel<<<2048, 256, 0, stream>>>(x,  xb, 2097152);
  cvt_kernel<<<2048, 256, 0, stream>>>(Wq, Wc, 1048576);
  cvt_kernel<<<1024, 256, 0, stream>>>(Wk, Wc + 4194304, 262144);
  cvt_kernel<<<1024, 256, 0, stream>>>(Wv, Wc + 5242880, 262144);
  gemm_bt<true><<<dim3(24, 32), 256, 0, stream>>>(xb, Wc, (void*)QKV, 4096, 3072, 2048);
  cvt_kernel<<<2048, 256, 0, stream>>>(Wo, Wc, 1048576);
  attn_kernel<<<dim3(16, 32), 256, 0, stream>>>(QKV, Ob);
  gemm_bt<false><<<dim3(16, 32), 256, 0, stream>>>(Ob, Wc, d_out, 4096, 2048, 2048);
}

// Round 4
// 250.173 us; speedup vs baseline: 1.9824x; 1.1719x over previous
//
#include <hip/hip_runtime.h>
#include <hip/hip_bf16.h>
#include <cstdint>
#include <cstddef>

using u16 = unsigned short;
typedef __bf16 bf16x8 __attribute__((ext_vector_type(8)));
typedef float f32x4 __attribute__((ext_vector_type(4)));
typedef float f32x16 __attribute__((ext_vector_type(16)));
typedef u16 u16x4 __attribute__((ext_vector_type(4)));
typedef u16 u16x8 __attribute__((ext_vector_type(8)));
typedef uint32_t u32x4 __attribute__((ext_vector_type(4)));

__device__ __forceinline__ u16 f2bf(float f) {
  uint32_t u = __builtin_bit_cast(uint32_t, f);
  u += 0x7FFFu + ((u >> 16) & 1u);   // RNE
  return (u16)(u >> 16);
}

__device__ __forceinline__ void gld_lds16(const void* g, void* l) {
  __builtin_amdgcn_global_load_lds(
      (const __attribute__((address_space(1))) unsigned int*)g,
      (__attribute__((address_space(3))) unsigned int*)l, 16, 0, 0);
}

#define MFMA16(a, b, c) __builtin_amdgcn_mfma_f32_16x16x32_bf16((a), (b), (c), 0, 0, 0)
#define MFMA32(a, b, c) __builtin_amdgcn_mfma_f32_32x32x16_bf16((a), (b), (c), 0, 0, 0)

__device__ __forceinline__ uint32_t pkbf(float a, float b) {
  uint32_t d;
  asm("v_cvt_pk_bf16_f32 %0, %1, %2" : "=v"(d) : "v"(a), "v"(b));
  return d;
}
__device__ __forceinline__ void swap32(uint32_t& a, uint32_t& b) {
  asm volatile("v_permlane32_swap_b32 %0, %1" : "+v"(a), "+v"(b));
}

// ---------------- fp32 -> bf16 convert ----------------
__global__ void cvt_kernel(const float* __restrict__ in, u16* __restrict__ out, int n4) {
  int i = blockIdx.x * blockDim.x + threadIdx.x;
  int stride = gridDim.x * blockDim.x;
  for (; i < n4; i += stride) {
    float4 v = reinterpret_cast<const float4*>(in)[i];
    u16x4 o;
    o[0] = f2bf(v.x); o[1] = f2bf(v.y); o[2] = f2bf(v.z); o[3] = f2bf(v.w);
    reinterpret_cast<u16x4*>(out)[i] = o;
  }
}

// ---------------- bf16 GEMM: C[M,N] = A[M,K] @ B[N,K]^T (m97 structure) ----------------
template <bool OUT_BF16>
__global__ __launch_bounds__(256) void gemm_bt(const u16* __restrict__ A,
                                               const u16* __restrict__ B,
                                               void* __restrict__ Cv,
                                               int M, int N, int K) {
  __shared__ __align__(16) u16 Ash[128 * 32];
  __shared__ __align__(16) u16 Bsh[128 * 32];
  const int tid = threadIdx.x;
  const int w = tid >> 6, lane = tid & 63, ql = lane & 15, g = lane >> 4;
  const int wr = w >> 1, wc = w & 1;
  const int m0 = blockIdx.y * 128, n0 = blockIdx.x * 128;
  const int srow = w * 16 + (lane >> 2);
  const int sk = (lane & 3) * 8;
  const u16* Abase = A + (size_t)(m0 + srow) * K + sk;
  const u16* Bbase = B + (size_t)(n0 + srow) * K + sk;

  f32x4 acc[4][4];
#pragma unroll
  for (int i = 0; i < 4; i++)
#pragma unroll
    for (int j = 0; j < 4; j++) acc[i][j] = f32x4{0.f, 0.f, 0.f, 0.f};

  for (int kt = 0; kt < K; kt += 32) {
    gld_lds16(Abase + kt,                  Ash + w * 512);
    gld_lds16(Abase + (size_t)64 * K + kt, Ash + 2048 + w * 512);
    gld_lds16(Bbase + kt,                  Bsh + w * 512);
    gld_lds16(Bbase + (size_t)64 * K + kt, Bsh + 2048 + w * 512);
    __syncthreads();
    bf16x8 af[4], bfr[4];
#pragma unroll
    for (int i = 0; i < 4; i++)
      af[i] = *reinterpret_cast<const bf16x8*>(&Ash[(wr * 64 + i * 16 + ql) * 32 + g * 8]);
#pragma unroll
    for (int j = 0; j < 4; j++)
      bfr[j] = *reinterpret_cast<const bf16x8*>(&Bsh[(wc * 64 + j * 16 + ql) * 32 + g * 8]);
#pragma unroll
    for (int i = 0; i < 4; i++)
#pragma unroll
      for (int j = 0; j < 4; j++)
        acc[i][j] = MFMA16(af[i], bfr[j], acc[i][j]);
    __syncthreads();
  }

#pragma unroll
  for (int i = 0; i < 4; i++)
#pragma unroll
    for (int j = 0; j < 4; j++)
#pragma unroll
      for (int r = 0; r < 4; r++) {
        const int row = m0 + wr * 64 + i * 16 + g * 4 + r;
        const int col = n0 + wc * 64 + j * 16 + ql;
        if constexpr (OUT_BF16)
          ((u16*)Cv)[(size_t)row * N + col] = f2bf(acc[i][j][r]);
        else
          ((float*)Cv)[(size_t)row * N + col] = acc[i][j][r];
      }
}

// ---------------- flash attention v4: 32x32 MFMA, in-register P, KVBLK=64 ----------------
// QKV: [4096][3072] bf16; O: [4096][2048]. grid (16 qt, 32 bh), block 256 = 4 waves.
// Wave owns 32 q. S^T = mfma(K,Q) (verified 32x32 C/D: col=lane&31,
// row=(r&3)+8(r>>2)+4(lane>>5)). Softmax in-lane + one xor-32 swap. P -> PV B-frags
// via v_cvt_pk_bf16_f32 + v_permlane32_swap (no P LDS). T13 defer-max, T14 V split.
__global__ __launch_bounds__(256, 2) void attn_kernel(const u16* __restrict__ QKV,
                                                      u16* __restrict__ O) {
  __shared__ __align__(16) u16 Kb[2][64 * 128];      // [s][128k], 16B-slot ^= (s&7)
  __shared__ __align__(16) u16 Vb[2][2][128 * 32];   // chunk=s>>5: V^T [d][32s], col ^= key(d)<<3
  const int tid = threadIdx.x, w = tid >> 6, lane = tid & 63;
  const int lq = lane & 31, hi = lane >> 5;
  const int qt = blockIdx.x;
  const int b = blockIdx.y >> 4, h = blockIdx.y & 15, hkv = h >> 2;
  const size_t rowb = (size_t)b * 2048;
  const int qbase = qt * 128 + w * 32;

  const u16* Kg = QKV + 2048 + hkv * 128;
  const u16* Vg = QKV + 2560 + hkv * 128;

  // Q B-frags: lane holds Q[q = qbase+lq][k = sl5*16 + hi*8 + j] (b128 global loads)
  bf16x8 bq[8];
  {
    const u16* qp = QKV + (rowb + qbase + lq) * 3072 + h * 128 + hi * 8;
#pragma unroll
    for (int s5 = 0; s5 < 8; s5++)
      bq[s5] = *reinterpret_cast<const bf16x8*>(qp + s5 * 16);
  }

  // V staging mapping: thread -> (sl = tid>>3 in [0,32), dg = tid&7 -> d = dg*16..+15), two s-halves
  const int dg = tid & 7, sl = tid >> 3;

  f32x16 oacc[4];
#pragma unroll
  for (int dt = 0; dt < 4; dt++)
#pragma unroll
    for (int i = 0; i < 16; i++) oacc[dt][i] = 0.f;
  float m = -INFINITY, l = 0.f;
  const float CEXP = 0.08838834764831845f * 1.4426950408889634f;  // scale*log2e

  auto stageK = [&](int pb2, int sbase) {
#pragma unroll
    for (int p = 0; p < 4; p++) {
      const int L = p * 2048 + tid * 8;
      const int s = L >> 7;
      const int gI = (L >> 3) & 15;
      gld_lds16(Kg + (rowb + sbase + s) * 3072 + ((gI ^ (s & 7)) << 3),
                &Kb[pb2][p * 2048 + w * 512]);
    }
  };
  auto writeV = [&](int pb2, const u16x8& a00, const u16x8& a01,
                    const u16x8& a10, const u16x8& a11) {
#pragma unroll
    for (int sh2 = 0; sh2 < 2; sh2++)
#pragma unroll
      for (int hf = 0; hf < 2; hf++) {
        const u16x8 v = sh2 ? (hf ? a11 : a10) : (hf ? a01 : a00);
#pragma unroll
        for (int j = 0; j < 8; j++) {
          const int d = dg * 16 + hf * 8 + j;
          const int key = ((d >> 1) ^ (d >> 4)) & 3;
          Vb[pb2][sh2][d * 32 + (sl ^ (key << 3))] = v[j];
        }
      }
  };

#define KFRAG(PB, SH, S5) \
  (*reinterpret_cast<const bf16x8*>(&Kb[PB][((SH)*32 + lq) * 128 + ((((S5)*2 + hi) ^ (lq & 7)) << 3)]))
#define VFRAG(PB, DT, SS) \
  (*reinterpret_cast<const bf16x8*>(&Vb[PB][(SS) >> 1][((DT)*32 + lq) * 32 + \
      ((((SS) & 1) * 16 + hi * 8) ^ (((((DT)*32 + lq) >> 1) ^ (((DT)*32 + lq) >> 4)) & 3) << 3)]))

  // ---- prologue: tile 0 ----
  u16x8 v00, v01, v10, v11;
  {
    const u16* vp = Vg + (rowb + sl) * 3072 + dg * 16;
    v00 = *reinterpret_cast<const u16x8*>(vp);
    v01 = *reinterpret_cast<const u16x8*>(vp + 8);
    const u16* vp2 = vp + (size_t)32 * 3072;
    v10 = *reinterpret_cast<const u16x8*>(vp2);
    v11 = *reinterpret_cast<const u16x8*>(vp2 + 8);
  }
  stageK(0, 0);
  writeV(0, v00, v01, v10, v11);
  __syncthreads();

#pragma unroll 1
  for (int sb = 0; sb < 32; sb++) {
    const int pb = sb & 1;
    // T14: issue next-tile loads first
    if (sb < 31) {
      const u16* vp = Vg + (rowb + (sb + 1) * 64 + sl) * 3072 + dg * 16;
      v00 = *reinterpret_cast<const u16x8*>(vp);
      v01 = *reinterpret_cast<const u16x8*>(vp + 8);
      const u16* vp2 = vp + (size_t)32 * 3072;
      v10 = *reinterpret_cast<const u16x8*>(vp2);
      v11 = *reinterpret_cast<const u16x8*>(vp2 + 8);
      stageK(pb ^ 1, (sb + 1) * 64);
    }

    // ---- S^T = K @ Q^T: two 32x32 C-tiles (s-halves) ----
    f32x16 sc0, sc1;
#pragma unroll
    for (int i = 0; i < 16; i++) { sc0[i] = 0.f; sc1[i] = 0.f; }
    __builtin_amdgcn_s_setprio(1);
#pragma unroll
    for (int s5 = 0; s5 < 8; s5++) {
      sc0 = MFMA32(KFRAG(pb, 0, s5), bq[s5], sc0);
      sc1 = MFMA32(KFRAG(pb, 1, s5), bq[s5], sc1);
    }
    __builtin_amdgcn_s_setprio(0);

    // ---- in-lane max over 32 s + partner swap ----
    float u[16];
#pragma unroll
    for (int i = 0; i < 16; i++) u[i] = fmaxf(sc0[i], sc1[i]);
#pragma unroll
    for (int i = 0; i < 8; i++) u[i] = fmaxf(u[i], u[i + 8]);
#pragma unroll
    for (int i = 0; i < 4; i++) u[i] = fmaxf(u[i], u[i + 4]);
    float mx = fmaxf(fmaxf(u[0], u[1]), fmaxf(u[2], u[3]));
    mx = fmaxf(mx, __shfl_xor(mx, 32));

    // ---- T13 defer-max ----
    if (__any((mx - m) * CEXP > 8.0f)) {
      const float mn = fmaxf(m, mx);
      const float corr = exp2f((m - mn) * CEXP);
      l *= corr;
#pragma unroll
      for (int dt = 0; dt < 4; dt++)
#pragma unroll
        for (int i = 0; i < 16; i++) oacc[dt][i] *= corr;
      m = mn;
    }

    // ---- exp + row-sum ----
    const float mC = m * CEXP;
    float e0[16], e1[16];
#pragma unroll
    for (int i = 0; i < 16; i++) {
      e0[i] = exp2f(fmaf(sc0[i], CEXP, -mC));
      e1[i] = exp2f(fmaf(sc1[i], CEXP, -mC));
    }
    float s[16];
#pragma unroll
    for (int i = 0; i < 16; i++) s[i] = e0[i] + e1[i];
#pragma unroll
    for (int i = 0; i < 8; i++) s[i] = s[i] + s[i + 8];
#pragma unroll
    for (int i = 0; i < 4; i++) s[i] = s[i] + s[i + 4];
    float ps = (s[0] + s[1]) + (s[2] + s[3]);
    ps += __shfl_xor(ps, 32);
    l += ps;

    // ---- pack P -> PV B-frags (cvt_pk + permlane32_swap; no LDS) ----
    bf16x8 pf0, pf1, pf2, pf3;
    {
      uint32_t a, bw;
      u32x4 f;
      a = pkbf(e0[0], e0[1]);  bw = pkbf(e0[4], e0[5]);  swap32(a, bw);
      f[0] = a; f[2] = bw;
      a = pkbf(e0[2], e0[3]);  bw = pkbf(e0[6], e0[7]);  swap32(a, bw);
      f[1] = a; f[3] = bw;
      pf0 = __builtin_bit_cast(bf16x8, f);
      a = pkbf(e0[8], e0[9]);  bw = pkbf(e0[12], e0[13]); swap32(a, bw);
      f[0] = a; f[2] = bw;
      a = pkbf(e0[10], e0[11]); bw = pkbf(e0[14], e0[15]); swap32(a, bw);
      f[1] = a; f[3] = bw;
      pf1 = __builtin_bit_cast(bf16x8, f);
      a = pkbf(e1[0], e1[1]);  bw = pkbf(e1[4], e1[5]);  swap32(a, bw);
      f[0] = a; f[2] = bw;
      a = pkbf(e1[2], e1[3]);  bw = pkbf(e1[6], e1[7]);  swap32(a, bw);
      f[1] = a; f[3] = bw;
      pf2 = __builtin_bit_cast(bf16x8, f);
      a = pkbf(e1[8], e1[9]);  bw = pkbf(e1[12], e1[13]); swap32(a, bw);
      f[0] = a; f[2] = bw;
      a = pkbf(e1[10], e1[11]); bw = pkbf(e1[14], e1[15]); swap32(a, bw);
      f[1] = a; f[3] = bw;
      pf3 = __builtin_bit_cast(bf16x8, f);
    }

    // ---- O^T += V^T @ P^T ----
    __builtin_amdgcn_s_setprio(1);
#pragma unroll
    for (int dt = 0; dt < 4; dt++) {
      oacc[dt] = MFMA32(VFRAG(pb, dt, 0), pf0, oacc[dt]);
      oacc[dt] = MFMA32(VFRAG(pb, dt, 1), pf1, oacc[dt]);
      oacc[dt] = MFMA32(VFRAG(pb, dt, 2), pf2, oacc[dt]);
      oacc[dt] = MFMA32(VFRAG(pb, dt, 3), pf3, oacc[dt]);
    }
    __builtin_amdgcn_s_setprio(0);

    if (sb < 31) writeV(pb ^ 1, v00, v01, v10, v11);  // write-late
    __syncthreads();
  }

  // ---- epilogue: normalize, per-wave LDS transpose (stride 136), coalesced store ----
  const float rl = 1.0f / l;
  u16* ob = (w < 2) ? &Kb[w][0] : &Vb[w - 2][0][0];  // 16 KB per wave region
#pragma unroll
  for (int dt = 0; dt < 4; dt++)
#pragma unroll
    for (int rq = 0; rq < 4; rq++) {
      u16x4 pv;
#pragma unroll
      for (int k = 0; k < 4; k++) pv[k] = f2bf(oacc[dt][rq * 4 + k] * rl);
      *reinterpret_cast<u16x4*>(&ob[lq * 136 + dt * 32 + rq * 8 + hi * 4]) = pv;
    }
  const int orow = lane >> 1, och = (lane & 1) * 64;
  u16* og = O + (rowb + qbase + orow) * 2048 + h * 128 + och;
#pragma unroll
  for (int t = 0; t < 8; t++) {
    u16x8 v = *reinterpret_cast<const u16x8*>(&ob[orow * 136 + och + t * 8]);
    *reinterpret_cast<u16x8*>(og + t * 8) = v;
  }
#undef KFRAG
#undef VFRAG
}

// ---------------- launch ----------------
extern "C" void kernel_launch(void* const* d_in, const int* in_sizes, int n_in,
                              void* d_out, int out_size, void* d_ws, size_t ws_size,
                              hipStream_t stream) {
  (void)in_sizes; (void)n_in; (void)out_size;
  const float* x  = (const float*)d_in[0];
  const float* Wq = (const float*)d_in[1];
  const float* Wk = (const float*)d_in[2];
  const float* Wv = (const float*)d_in[3];
  const float* Wo = (const float*)d_in[4];

  if (ws_size < (size_t)(8388608 + 6291456 + 12582912) * 2) return;
  u16* xb  = (u16*)d_ws;
  u16* Wc  = xb + 8388608;
  u16* QKV = Wc + 6291456;
  u16* Ob  = xb;  // reuse x-bf16 region for attention output

  cvt_kernel<<<2048, 256, 0, stream>>>(x,  xb, 2097152);
  cvt_kernel<<<2048, 256, 0, stream>>>(Wq, Wc, 1048576);
  cvt_kernel<<<1024, 256, 0, stream>>>(Wk, Wc + 4194304, 262144);
  cvt_kernel<<<1024, 256, 0, stream>>>(Wv, Wc + 5242880, 262144);
  gemm_bt<true><<<dim3(24, 32), 256, 0, stream>>>(xb, Wc, (void*)QKV, 4096, 3072, 2048);
  cvt_kernel<<<2048, 256, 0, stream>>>(Wo, Wc, 1048576);
  attn_kernel<<<dim3(16, 32), 256, 0, stream>>>(QKV, Ob);
  gemm_bt<false><<<dim3(16, 32), 256, 0, stream>>>(Ob, Wc, d_out, 4096, 2048, 2048);
}

// Round 5
// 237.317 us; speedup vs baseline: 2.0898x; 1.0542x over previous
//
#include <hip/hip_runtime.h>
#include <hip/hip_bf16.h>
#include <cstdint>
#include <cstddef>

using u16 = unsigned short;
typedef __bf16 bf16x8 __attribute__((ext_vector_type(8)));
typedef float f32x4 __attribute__((ext_vector_type(4)));
typedef float f32x16 __attribute__((ext_vector_type(16)));
typedef u16 u16x4 __attribute__((ext_vector_type(4)));
typedef u16 u16x8 __attribute__((ext_vector_type(8)));
typedef uint32_t u32x4 __attribute__((ext_vector_type(4)));

__device__ __forceinline__ u16 f2bf(float f) {
  uint32_t u = __builtin_bit_cast(uint32_t, f);
  u += 0x7FFFu + ((u >> 16) & 1u);   // RNE
  return (u16)(u >> 16);
}

__device__ __forceinline__ void gld_lds16(const void* g, void* l) {
  __builtin_amdgcn_global_load_lds(
      (const __attribute__((address_space(1))) unsigned int*)g,
      (__attribute__((address_space(3))) unsigned int*)l, 16, 0, 0);
}

#define MFMA16(a, b, c) __builtin_amdgcn_mfma_f32_16x16x32_bf16((a), (b), (c), 0, 0, 0)
#define MFMA32(a, b, c) __builtin_amdgcn_mfma_f32_32x32x16_bf16((a), (b), (c), 0, 0, 0)

__device__ __forceinline__ uint32_t pkbf(float a, float b) {
  uint32_t d;
  asm("v_cvt_pk_bf16_f32 %0, %1, %2" : "=v"(d) : "v"(a), "v"(b));
  return d;
}
__device__ __forceinline__ void swap32(uint32_t& a, uint32_t& b) {
  asm volatile("v_permlane32_swap_b32 %0, %1" : "+v"(a), "+v"(b));
}

// ---------------- fp32 -> bf16 convert ----------------
__global__ void cvt_kernel(const float* __restrict__ in, u16* __restrict__ out, int n4) {
  int i = blockIdx.x * blockDim.x + threadIdx.x;
  int stride = gridDim.x * blockDim.x;
  for (; i < n4; i += stride) {
    float4 v = reinterpret_cast<const float4*>(in)[i];
    u16x4 o;
    o[0] = f2bf(v.x); o[1] = f2bf(v.y); o[2] = f2bf(v.z); o[3] = f2bf(v.w);
    reinterpret_cast<u16x4*>(out)[i] = o;
  }
}

// ---------------- bf16 GEMM: C[M,N] = A[M,K] @ B[N,K]^T ----------------
// m97 fragment structure + T3/T4 pipeline: triple-buffered BK=32 tiles,
// stage tile t+2 while computing tile t, counted vmcnt(4) (never 0 in loop),
// raw s_barrier (no compiler vmcnt(0) drain). Race-free: buffer written at
// iter t+1 was last read at iter t (lgkm-confirmed before iter-t barrier).
template <bool OUT_BF16>
__global__ __launch_bounds__(256) void gemm_bt(const u16* __restrict__ A,
                                               const u16* __restrict__ B,
                                               void* __restrict__ Cv,
                                               int M, int N, int K) {
  __shared__ __align__(16) u16 Ash[3][128 * 32];
  __shared__ __align__(16) u16 Bsh[3][128 * 32];
  const int tid = threadIdx.x;
  const int w = tid >> 6, lane = tid & 63, ql = lane & 15, g = lane >> 4;
  const int wr = w >> 1, wc = w & 1;
  const int m0 = blockIdx.y * 128, n0 = blockIdx.x * 128;
  const int srow = w * 16 + (lane >> 2);
  const int sk = (lane & 3) * 8;
  const u16* Abase = A + (size_t)(m0 + srow) * K + sk;
  const u16* Bbase = B + (size_t)(n0 + srow) * K + sk;

  f32x4 acc[4][4];
#pragma unroll
  for (int i = 0; i < 4; i++)
#pragma unroll
    for (int j = 0; j < 4; j++) acc[i][j] = f32x4{0.f, 0.f, 0.f, 0.f};

  auto stage = [&](int bi, int tile) {
    const int kt = tile * 32;
    gld_lds16(Abase + kt,                  &Ash[bi][w * 512]);
    gld_lds16(Abase + (size_t)64 * K + kt, &Ash[bi][2048 + w * 512]);
    gld_lds16(Bbase + kt,                  &Bsh[bi][w * 512]);
    gld_lds16(Bbase + (size_t)64 * K + kt, &Bsh[bi][2048 + w * 512]);
  };

  const int nt = K >> 5;
  // ---- prologue: stage tiles 0,1; wait tile 0 (tile 1's 4 loads in flight) ----
  stage(0, 0);
  stage(1, 1);
  asm volatile("s_waitcnt vmcnt(4)" ::: "memory");
  __builtin_amdgcn_sched_barrier(0);
  __builtin_amdgcn_s_barrier();
  __builtin_amdgcn_sched_barrier(0);

  int cur = 0;
  for (int t = 0; t < nt; ++t) {
    if (t + 2 < nt) {
      int stg = cur + 2; if (stg >= 3) stg -= 3;
      stage(stg, t + 2);
    }
    bf16x8 af[4], bfr[4];
#pragma unroll
    for (int i = 0; i < 4; i++)
      af[i] = *reinterpret_cast<const bf16x8*>(&Ash[cur][(wr * 64 + i * 16 + ql) * 32 + g * 8]);
#pragma unroll
    for (int j = 0; j < 4; j++)
      bfr[j] = *reinterpret_cast<const bf16x8*>(&Bsh[cur][(wc * 64 + j * 16 + ql) * 32 + g * 8]);
    __builtin_amdgcn_s_setprio(1);
#pragma unroll
    for (int i = 0; i < 4; i++)
#pragma unroll
      for (int j = 0; j < 4; j++)
        acc[i][j] = MFMA16(af[i], bfr[j], acc[i][j]);
    __builtin_amdgcn_s_setprio(0);
    if (t + 1 < nt) {
      if (t + 2 < nt) {
        asm volatile("s_waitcnt vmcnt(4)" ::: "memory");  // tile t+1 landed; t+2 in flight
      } else {
        asm volatile("s_waitcnt vmcnt(0)" ::: "memory");  // drain for final tile
      }
      __builtin_amdgcn_sched_barrier(0);
      __builtin_amdgcn_s_barrier();
      __builtin_amdgcn_sched_barrier(0);
    }
    cur = (cur == 2) ? 0 : cur + 1;
  }

#pragma unroll
  for (int i = 0; i < 4; i++)
#pragma unroll
    for (int j = 0; j < 4; j++)
#pragma unroll
      for (int r = 0; r < 4; r++) {
        const int row = m0 + wr * 64 + i * 16 + g * 4 + r;
        const int col = n0 + wc * 64 + j * 16 + ql;
        if constexpr (OUT_BF16)
          ((u16*)Cv)[(size_t)row * N + col] = f2bf(acc[i][j][r]);
        else
          ((float*)Cv)[(size_t)row * N + col] = acc[i][j][r];
      }
}

// ---------------- flash attention v4: 32x32 MFMA, in-register P, KVBLK=64 ----------------
// (unchanged from R4 — single-variable discipline)
__global__ __launch_bounds__(256, 2) void attn_kernel(const u16* __restrict__ QKV,
                                                      u16* __restrict__ O) {
  __shared__ __align__(16) u16 Kb[2][64 * 128];      // [s][128k], 16B-slot ^= (s&7)
  __shared__ __align__(16) u16 Vb[2][2][128 * 32];   // chunk=s>>5: V^T [d][32s], col ^= key(d)<<3
  const int tid = threadIdx.x, w = tid >> 6, lane = tid & 63;
  const int lq = lane & 31, hi = lane >> 5;
  const int qt = blockIdx.x;
  const int b = blockIdx.y >> 4, h = blockIdx.y & 15, hkv = h >> 2;
  const size_t rowb = (size_t)b * 2048;
  const int qbase = qt * 128 + w * 32;

  const u16* Kg = QKV + 2048 + hkv * 128;
  const u16* Vg = QKV + 2560 + hkv * 128;

  bf16x8 bq[8];
  {
    const u16* qp = QKV + (rowb + qbase + lq) * 3072 + h * 128 + hi * 8;
#pragma unroll
    for (int s5 = 0; s5 < 8; s5++)
      bq[s5] = *reinterpret_cast<const bf16x8*>(qp + s5 * 16);
  }

  const int dg = tid & 7, sl = tid >> 3;

  f32x16 oacc[4];
#pragma unroll
  for (int dt = 0; dt < 4; dt++)
#pragma unroll
    for (int i = 0; i < 16; i++) oacc[dt][i] = 0.f;
  float m = -INFINITY, l = 0.f;
  const float CEXP = 0.08838834764831845f * 1.4426950408889634f;  // scale*log2e

  auto stageK = [&](int pb2, int sbase) {
#pragma unroll
    for (int p = 0; p < 4; p++) {
      const int L = p * 2048 + tid * 8;
      const int s = L >> 7;
      const int gI = (L >> 3) & 15;
      gld_lds16(Kg + (rowb + sbase + s) * 3072 + ((gI ^ (s & 7)) << 3),
                &Kb[pb2][p * 2048 + w * 512]);
    }
  };
  auto writeV = [&](int pb2, const u16x8& a00, const u16x8& a01,
                    const u16x8& a10, const u16x8& a11) {
#pragma unroll
    for (int sh2 = 0; sh2 < 2; sh2++)
#pragma unroll
      for (int hf = 0; hf < 2; hf++) {
        const u16x8 v = sh2 ? (hf ? a11 : a10) : (hf ? a01 : a00);
#pragma unroll
        for (int j = 0; j < 8; j++) {
          const int d = dg * 16 + hf * 8 + j;
          const int key = ((d >> 1) ^ (d >> 4)) & 3;
          Vb[pb2][sh2][d * 32 + (sl ^ (key << 3))] = v[j];
        }
      }
  };

#define KFRAG(PB, SH, S5) \
  (*reinterpret_cast<const bf16x8*>(&Kb[PB][((SH)*32 + lq) * 128 + ((((S5)*2 + hi) ^ (lq & 7)) << 3)]))
#define VFRAG(PB, DT, SS) \
  (*reinterpret_cast<const bf16x8*>(&Vb[PB][(SS) >> 1][((DT)*32 + lq) * 32 + \
      ((((SS) & 1) * 16 + hi * 8) ^ (((((DT)*32 + lq) >> 1) ^ (((DT)*32 + lq) >> 4)) & 3) << 3)]))

  u16x8 v00, v01, v10, v11;
  {
    const u16* vp = Vg + (rowb + sl) * 3072 + dg * 16;
    v00 = *reinterpret_cast<const u16x8*>(vp);
    v01 = *reinterpret_cast<const u16x8*>(vp + 8);
    const u16* vp2 = vp + (size_t)32 * 3072;
    v10 = *reinterpret_cast<const u16x8*>(vp2);
    v11 = *reinterpret_cast<const u16x8*>(vp2 + 8);
  }
  stageK(0, 0);
  writeV(0, v00, v01, v10, v11);
  __syncthreads();

#pragma unroll 1
  for (int sb = 0; sb < 32; sb++) {
    const int pb = sb & 1;
    if (sb < 31) {
      const u16* vp = Vg + (rowb + (sb + 1) * 64 + sl) * 3072 + dg * 16;
      v00 = *reinterpret_cast<const u16x8*>(vp);
      v01 = *reinterpret_cast<const u16x8*>(vp + 8);
      const u16* vp2 = vp + (size_t)32 * 3072;
      v10 = *reinterpret_cast<const u16x8*>(vp2);
      v11 = *reinterpret_cast<const u16x8*>(vp2 + 8);
      stageK(pb ^ 1, (sb + 1) * 64);
    }

    f32x16 sc0, sc1;
#pragma unroll
    for (int i = 0; i < 16; i++) { sc0[i] = 0.f; sc1[i] = 0.f; }
    __builtin_amdgcn_s_setprio(1);
#pragma unroll
    for (int s5 = 0; s5 < 8; s5++) {
      sc0 = MFMA32(KFRAG(pb, 0, s5), bq[s5], sc0);
      sc1 = MFMA32(KFRAG(pb, 1, s5), bq[s5], sc1);
    }
    __builtin_amdgcn_s_setprio(0);

    float u[16];
#pragma unroll
    for (int i = 0; i < 16; i++) u[i] = fmaxf(sc0[i], sc1[i]);
#pragma unroll
    for (int i = 0; i < 8; i++) u[i] = fmaxf(u[i], u[i + 8]);
#pragma unroll
    for (int i = 0; i < 4; i++) u[i] = fmaxf(u[i], u[i + 4]);
    float mx = fmaxf(fmaxf(u[0], u[1]), fmaxf(u[2], u[3]));
    mx = fmaxf(mx, __shfl_xor(mx, 32));

    if (__any((mx - m) * CEXP > 8.0f)) {
      const float mn = fmaxf(m, mx);
      const float corr = exp2f((m - mn) * CEXP);
      l *= corr;
#pragma unroll
      for (int dt = 0; dt < 4; dt++)
#pragma unroll
        for (int i = 0; i < 16; i++) oacc[dt][i] *= corr;
      m = mn;
    }

    const float mC = m * CEXP;
    float e0[16], e1[16];
#pragma unroll
    for (int i = 0; i < 16; i++) {
      e0[i] = exp2f(fmaf(sc0[i], CEXP, -mC));
      e1[i] = exp2f(fmaf(sc1[i], CEXP, -mC));
    }
    float s[16];
#pragma unroll
    for (int i = 0; i < 16; i++) s[i] = e0[i] + e1[i];
#pragma unroll
    for (int i = 0; i < 8; i++) s[i] = s[i] + s[i + 8];
#pragma unroll
    for (int i = 0; i < 4; i++) s[i] = s[i] + s[i + 4];
    float ps = (s[0] + s[1]) + (s[2] + s[3]);
    ps += __shfl_xor(ps, 32);
    l += ps;

    bf16x8 pf0, pf1, pf2, pf3;
    {
      uint32_t a, bw;
      u32x4 f;
      a = pkbf(e0[0], e0[1]);  bw = pkbf(e0[4], e0[5]);  swap32(a, bw);
      f[0] = a; f[2] = bw;
      a = pkbf(e0[2], e0[3]);  bw = pkbf(e0[6], e0[7]);  swap32(a, bw);
      f[1] = a; f[3] = bw;
      pf0 = __builtin_bit_cast(bf16x8, f);
      a = pkbf(e0[8], e0[9]);  bw = pkbf(e0[12], e0[13]); swap32(a, bw);
      f[0] = a; f[2] = bw;
      a = pkbf(e0[10], e0[11]); bw = pkbf(e0[14], e0[15]); swap32(a, bw);
      f[1] = a; f[3] = bw;
      pf1 = __builtin_bit_cast(bf16x8, f);
      a = pkbf(e1[0], e1[1]);  bw = pkbf(e1[4], e1[5]);  swap32(a, bw);
      f[0] = a; f[2] = bw;
      a = pkbf(e1[2], e1[3]);  bw = pkbf(e1[6], e1[7]);  swap32(a, bw);
      f[1] = a; f[3] = bw;
      pf2 = __builtin_bit_cast(bf16x8, f);
      a = pkbf(e1[8], e1[9]);  bw = pkbf(e1[12], e1[13]); swap32(a, bw);
      f[0] = a; f[2] = bw;
      a = pkbf(e1[10], e1[11]); bw = pkbf(e1[14], e1[15]); swap32(a, bw);
      f[1] = a; f[3] = bw;
      pf3 = __builtin_bit_cast(bf16x8, f);
    }

    __builtin_amdgcn_s_setprio(1);
#pragma unroll
    for (int dt = 0; dt < 4; dt++) {
      oacc[dt] = MFMA32(VFRAG(pb, dt, 0), pf0, oacc[dt]);
      oacc[dt] = MFMA32(VFRAG(pb, dt, 1), pf1, oacc[dt]);
      oacc[dt] = MFMA32(VFRAG(pb, dt, 2), pf2, oacc[dt]);
      oacc[dt] = MFMA32(VFRAG(pb, dt, 3), pf3, oacc[dt]);
    }
    __builtin_amdgcn_s_setprio(0);

    if (sb < 31) writeV(pb ^ 1, v00, v01, v10, v11);
    __syncthreads();
  }

  const float rl = 1.0f / l;
  u16* ob = (w < 2) ? &Kb[w][0] : &Vb[w - 2][0][0];
#pragma unroll
  for (int dt = 0; dt < 4; dt++)
#pragma unroll
    for (int rq = 0; rq < 4; rq++) {
      u16x4 pv;
#pragma unroll
      for (int k = 0; k < 4; k++) pv[k] = f2bf(oacc[dt][rq * 4 + k] * rl);
      *reinterpret_cast<u16x4*>(&ob[lq * 136 + dt * 32 + rq * 8 + hi * 4]) = pv;
    }
  const int orow = lane >> 1, och = (lane & 1) * 64;
  u16* og = O + (rowb + qbase + orow) * 2048 + h * 128 + och;
#pragma unroll
  for (int t = 0; t < 8; t++) {
    u16x8 v = *reinterpret_cast<const u16x8*>(&ob[orow * 136 + och + t * 8]);
    *reinterpret_cast<u16x8*>(og + t * 8) = v;
  }
#undef KFRAG
#undef VFRAG
}

// ---------------- launch ----------------
extern "C" void kernel_launch(void* const* d_in, const int* in_sizes, int n_in,
                              void* d_out, int out_size, void* d_ws, size_t ws_size,
                              hipStream_t stream) {
  (void)in_sizes; (void)n_in; (void)out_size;
  const float* x  = (const float*)d_in[0];
  const float* Wq = (const float*)d_in[1];
  const float* Wk = (const float*)d_in[2];
  const float* Wv = (const float*)d_in[3];
  const float* Wo = (const float*)d_in[4];

  if (ws_size < (size_t)(8388608 + 6291456 + 12582912) * 2) return;
  u16* xb  = (u16*)d_ws;
  u16* Wc  = xb + 8388608;
  u16* QKV = Wc + 6291456;
  u16* Ob  = xb;  // reuse x-bf16 region for attention output

  cvt_kernel<<<2048, 256, 0, stream>>>(x,  xb, 2097152);
  cvt_kernel<<<2048, 256, 0, stream>>>(Wq, Wc, 1048576);
  cvt_kernel<<<1024, 256, 0, stream>>>(Wk, Wc + 4194304, 262144);
  cvt_kernel<<<1024, 256, 0, stream>>>(Wv, Wc + 5242880, 262144);
  gemm_bt<true><<<dim3(24, 32), 256, 0, stream>>>(xb, Wc, (void*)QKV, 4096, 3072, 2048);
  cvt_kernel<<<2048, 256, 0, stream>>>(Wo, Wc, 1048576);
  attn_kernel<<<dim3(16, 32), 256, 0, stream>>>(QKV, Ob);
  gemm_bt<false><<<dim3(16, 32), 256, 0, stream>>>(Ob, Wc, d_out, 4096, 2048, 2048);
}

// Round 7
// 233.200 us; speedup vs baseline: 2.1267x; 1.0177x over previous
//
#include <hip/hip_runtime.h>
#include <hip/hip_bf16.h>
#include <cstdint>
#include <cstddef>

using u16 = unsigned short;
typedef __bf16 bf16x8 __attribute__((ext_vector_type(8)));
typedef float f32x4 __attribute__((ext_vector_type(4)));
typedef float f32x16 __attribute__((ext_vector_type(16)));
typedef u16 u16x4 __attribute__((ext_vector_type(4)));
typedef u16 u16x8 __attribute__((ext_vector_type(8)));
typedef uint32_t u32x4 __attribute__((ext_vector_type(4)));

__device__ __forceinline__ u16 f2bf(float f) {
  uint32_t u = __builtin_bit_cast(uint32_t, f);
  u += 0x7FFFu + ((u >> 16) & 1u);   // RNE
  return (u16)(u >> 16);
}

__device__ __forceinline__ void gld_lds16(const void* g, void* l) {
  __builtin_amdgcn_global_load_lds(
      (const __attribute__((address_space(1))) unsigned int*)g,
      (__attribute__((address_space(3))) unsigned int*)l, 16, 0, 0);
}

#define MFMA16(a, b, c) __builtin_amdgcn_mfma_f32_16x16x32_bf16((a), (b), (c), 0, 0, 0)
#define MFMA32(a, b, c) __builtin_amdgcn_mfma_f32_32x32x16_bf16((a), (b), (c), 0, 0, 0)

__device__ __forceinline__ uint32_t pkbf(float a, float b) {
  uint32_t d;
  asm("v_cvt_pk_bf16_f32 %0, %1, %2" : "=v"(d) : "v"(a), "v"(b));
  return d;
}
__device__ __forceinline__ void swap32(uint32_t& a, uint32_t& b) {
  asm volatile("v_permlane32_swap_b32 %0, %1" : "+v"(a), "+v"(b));
}

// ---------------- fp32 -> bf16 converts ----------------
__global__ void cvt_kernel(const float* __restrict__ in, u16* __restrict__ out, int n4) {
  int i = blockIdx.x * blockDim.x + threadIdx.x;
  int stride = gridDim.x * blockDim.x;
  for (; i < n4; i += stride) {
    float4 v = reinterpret_cast<const float4*>(in)[i];
    u16x4 o;
    o[0] = f2bf(v.x); o[1] = f2bf(v.y); o[2] = f2bf(v.z); o[3] = f2bf(v.w);
    reinterpret_cast<u16x4*>(out)[i] = o;
  }
}

// merged x/Wq/Wk/Wv convert (one launch instead of four)
__global__ void cvt4_kernel(const float* __restrict__ x, const float* __restrict__ Wq,
                            const float* __restrict__ Wk, const float* __restrict__ Wv,
                            u16* __restrict__ xb, u16* __restrict__ Wc) {
  int i = blockIdx.x * blockDim.x + threadIdx.x;
  int stride = gridDim.x * blockDim.x;
  for (; i < 3670016; i += stride) {
    const float* src; u16* dst; int off;
    if (i < 2097152)      { src = x;  dst = xb;            off = i; }
    else if (i < 3145728) { src = Wq; dst = Wc;            off = i - 2097152; }
    else if (i < 3407872) { src = Wk; dst = Wc + 4194304;  off = i - 3145728; }
    else                  { src = Wv; dst = Wc + 5242880;  off = i - 3407872; }
    float4 v = reinterpret_cast<const float4*>(src)[off];
    u16x4 o;
    o[0] = f2bf(v.x); o[1] = f2bf(v.y); o[2] = f2bf(v.z); o[3] = f2bf(v.w);
    reinterpret_cast<u16x4*>(dst)[off] = o;
  }
}

// ---------------- bf16 GEMM: C[M,N] = A[M,K] @ B[N,K]^T ----------------
// m97 fragment structure + T3/T4 triple-buffer pipeline (unchanged).
template <bool OUT_BF16>
__global__ __launch_bounds__(256) void gemm_bt(const u16* __restrict__ A,
                                               const u16* __restrict__ B,
                                               void* __restrict__ Cv,
                                               int M, int N, int K) {
  __shared__ __align__(16) u16 Ash[3][128 * 32];
  __shared__ __align__(16) u16 Bsh[3][128 * 32];
  const int tid = threadIdx.x;
  const int w = tid >> 6, lane = tid & 63, ql = lane & 15, g = lane >> 4;
  const int wr = w >> 1, wc = w & 1;
  const int m0 = blockIdx.y * 128, n0 = blockIdx.x * 128;
  const int srow = w * 16 + (lane >> 2);
  const int sk = (lane & 3) * 8;
  const u16* Abase = A + (size_t)(m0 + srow) * K + sk;
  const u16* Bbase = B + (size_t)(n0 + srow) * K + sk;

  f32x4 acc[4][4];
#pragma unroll
  for (int i = 0; i < 4; i++)
#pragma unroll
    for (int j = 0; j < 4; j++) acc[i][j] = f32x4{0.f, 0.f, 0.f, 0.f};

  auto stage = [&](int bi, int tile) {
    const int kt = tile * 32;
    gld_lds16(Abase + kt,                  &Ash[bi][w * 512]);
    gld_lds16(Abase + (size_t)64 * K + kt, &Ash[bi][2048 + w * 512]);
    gld_lds16(Bbase + kt,                  &Bsh[bi][w * 512]);
    gld_lds16(Bbase + (size_t)64 * K + kt, &Bsh[bi][2048 + w * 512]);
  };

  const int nt = K >> 5;
  stage(0, 0);
  stage(1, 1);
  asm volatile("s_waitcnt vmcnt(4)" ::: "memory");
  __builtin_amdgcn_sched_barrier(0);
  __builtin_amdgcn_s_barrier();
  __builtin_amdgcn_sched_barrier(0);

  int cur = 0;
  for (int t = 0; t < nt; ++t) {
    if (t + 2 < nt) {
      int stg = cur + 2; if (stg >= 3) stg -= 3;
      stage(stg, t + 2);
    }
    bf16x8 af[4], bfr[4];
#pragma unroll
    for (int i = 0; i < 4; i++)
      af[i] = *reinterpret_cast<const bf16x8*>(&Ash[cur][(wr * 64 + i * 16 + ql) * 32 + g * 8]);
#pragma unroll
    for (int j = 0; j < 4; j++)
      bfr[j] = *reinterpret_cast<const bf16x8*>(&Bsh[cur][(wc * 64 + j * 16 + ql) * 32 + g * 8]);
    __builtin_amdgcn_s_setprio(1);
#pragma unroll
    for (int i = 0; i < 4; i++)
#pragma unroll
      for (int j = 0; j < 4; j++)
        acc[i][j] = MFMA16(af[i], bfr[j], acc[i][j]);
    __builtin_amdgcn_s_setprio(0);
    if (t + 1 < nt) {
      if (t + 2 < nt) {
        asm volatile("s_waitcnt vmcnt(4)" ::: "memory");
      } else {
        asm volatile("s_waitcnt vmcnt(0)" ::: "memory");
      }
      __builtin_amdgcn_sched_barrier(0);
      __builtin_amdgcn_s_barrier();
      __builtin_amdgcn_sched_barrier(0);
    }
    cur = (cur == 2) ? 0 : cur + 1;
  }

#pragma unroll
  for (int i = 0; i < 4; i++)
#pragma unroll
    for (int j = 0; j < 4; j++)
#pragma unroll
      for (int r = 0; r < 4; r++) {
        const int row = m0 + wr * 64 + i * 16 + g * 4 + r;
        const int col = n0 + wc * 64 + j * 16 + ql;
        if constexpr (OUT_BF16)
          ((u16*)Cv)[(size_t)row * N + col] = f2bf(acc[i][j][r]);
        else
          ((float*)Cv)[(size_t)row * N + col] = acc[i][j][r];
      }
}

// ---------------- flash attention v5b ----------------
// v5 + FIX: epilogue scratch for waves 2/3 is &Vb[w-2][0][0] (8192-u16 stride,
// disjoint 4344-u16 regions). v5's &Vb[0][w-2][0] gave only 4096-u16 stride ->
// waves 2/3 overlapped -> corrupted O (R6 absmax 0.175).
__global__ __launch_bounds__(256, 2) void attn_kernel(const u16* __restrict__ QKV,
                                                      u16* __restrict__ O) {
  __shared__ __align__(16) u16 Kb[2][64 * 128];      // [s][128k], 16B-slot ^= (s&7)
  __shared__ __align__(16) u16 Vb[3][2][128 * 32];   // 3 bufs: chunk=s>>5: V^T [d][32s]
  const int tid = threadIdx.x, w = tid >> 6, lane = tid & 63;
  const int lq = lane & 31, hi = lane >> 5;
  // XCD swizzle: bid%8 -> XCD; give each XCD 64 consecutive work ids = 4 bh = 1 (b,hkv)
  const int bid = blockIdx.x;
  const int swz = (bid & 7) * 64 + (bid >> 3);
  const int qt = swz & 15;
  const int bh = swz >> 4;
  const int b = bh >> 4, h = bh & 15, hkv = h >> 2;
  const size_t rowb = (size_t)b * 2048;
  const int qbase = qt * 128 + w * 32;

  const u16* Kg = QKV + 2048 + hkv * 128;
  const u16* Vg = QKV + 2560 + hkv * 128;

  bf16x8 bq[8];
  {
    const u16* qp = QKV + (rowb + qbase + lq) * 3072 + h * 128 + hi * 8;
#pragma unroll
    for (int s5 = 0; s5 < 8; s5++)
      bq[s5] = *reinterpret_cast<const bf16x8*>(qp + s5 * 16);
  }

  const int dg = tid & 7, sl = tid >> 3;

  f32x16 oacc[4], lacc;
#pragma unroll
  for (int dt = 0; dt < 4; dt++)
#pragma unroll
    for (int i = 0; i < 16; i++) oacc[dt][i] = 0.f;
#pragma unroll
  for (int i = 0; i < 16; i++) lacc[i] = 0.f;
  float m = -INFINITY;
  const float CEXP = 0.08838834764831845f * 1.4426950408889634f;  // scale*log2e

  const bf16x8 ones = __builtin_bit_cast(bf16x8,
      u32x4{0x3F803F80u, 0x3F803F80u, 0x3F803F80u, 0x3F803F80u});

  auto stageK = [&](int pb2, int sbase) {
#pragma unroll
    for (int p = 0; p < 4; p++) {
      const int L = p * 2048 + tid * 8;
      const int s = L >> 7;
      const int gI = (L >> 3) & 15;
      gld_lds16(Kg + (rowb + sbase + s) * 3072 + ((gI ^ (s & 7)) << 3),
                &Kb[pb2][p * 2048 + w * 512]);
    }
  };
  auto writeV = [&](int vb3, const u16x8& a00, const u16x8& a01,
                    const u16x8& a10, const u16x8& a11) {
#pragma unroll
    for (int sh2 = 0; sh2 < 2; sh2++)
#pragma unroll
      for (int hf = 0; hf < 2; hf++) {
        const u16x8 v = sh2 ? (hf ? a11 : a10) : (hf ? a01 : a00);
#pragma unroll
        for (int j = 0; j < 8; j++) {
          const int d = dg * 16 + hf * 8 + j;
          const int key = ((d >> 1) ^ (d >> 4)) & 3;
          Vb[vb3][sh2][d * 32 + (sl ^ (key << 3))] = v[j];
        }
      }
  };

#define KFRAG(PB, SH, S5) \
  (*reinterpret_cast<const bf16x8*>(&Kb[PB][((SH)*32 + lq) * 128 + ((((S5)*2 + hi) ^ (lq & 7)) << 3)]))
#define VFRAG(VB, DT, SS) \
  (*reinterpret_cast<const bf16x8*>(&Vb[VB][(SS) >> 1][((DT)*32 + lq) * 32 + \
      ((((SS) & 1) * 16 + hi * 8) ^ (((((DT)*32 + lq) >> 1) ^ (((DT)*32 + lq) >> 4)) & 3) << 3)]))

  u16x8 v00, v01, v10, v11;
  {
    const u16* vp = Vg + (rowb + sl) * 3072 + dg * 16;
    v00 = *reinterpret_cast<const u16x8*>(vp);
    v01 = *reinterpret_cast<const u16x8*>(vp + 8);
    const u16* vp2 = vp + (size_t)32 * 3072;
    v10 = *reinterpret_cast<const u16x8*>(vp2);
    v11 = *reinterpret_cast<const u16x8*>(vp2 + 8);
  }
  stageK(0, 0);
  writeV(0, v00, v01, v10, v11);
  __syncthreads();

  bf16x8 pf0, pf1, pf2, pf3;   // P frags of PREVIOUS tile during iteration body
  int vprev = 2, vcur = 0, vnext = 1;

#pragma unroll 1
  for (int sb = 0; sb < 32; sb++) {
    const int pb = sb & 1;
    // T14: issue next-tile loads first
    if (sb < 31) {
      const u16* vp = Vg + (rowb + (sb + 1) * 64 + sl) * 3072 + dg * 16;
      v00 = *reinterpret_cast<const u16x8*>(vp);
      v01 = *reinterpret_cast<const u16x8*>(vp + 8);
      const u16* vp2 = vp + (size_t)32 * 3072;
      v10 = *reinterpret_cast<const u16x8*>(vp2);
      v11 = *reinterpret_cast<const u16x8*>(vp2 + 8);
      stageK(pb ^ 1, (sb + 1) * 64);
    }

    // ---- S^T = K @ Q^T ----
    f32x16 sc0, sc1;
#pragma unroll
    for (int i = 0; i < 16; i++) { sc0[i] = 0.f; sc1[i] = 0.f; }
    __builtin_amdgcn_s_setprio(1);
#pragma unroll
    for (int s5 = 0; s5 < 8; s5++) {
      sc0 = MFMA32(KFRAG(pb, 0, s5), bq[s5], sc0);
      sc1 = MFMA32(KFRAG(pb, 1, s5), bq[s5], sc1);
    }
    __builtin_amdgcn_s_setprio(0);

    // ---- deferred PV(t-1): independent of sc -> hides QK->max latency ----
    if (sb) {
      __builtin_amdgcn_s_setprio(1);
#pragma unroll
      for (int dt = 0; dt < 4; dt++) {
        oacc[dt] = MFMA32(VFRAG(vprev, dt, 0), pf0, oacc[dt]);
        oacc[dt] = MFMA32(VFRAG(vprev, dt, 1), pf1, oacc[dt]);
        oacc[dt] = MFMA32(VFRAG(vprev, dt, 2), pf2, oacc[dt]);
        oacc[dt] = MFMA32(VFRAG(vprev, dt, 3), pf3, oacc[dt]);
      }
      __builtin_amdgcn_s_setprio(0);
    }

    // ---- in-lane max + partner swap ----
    float u[16];
#pragma unroll
    for (int i = 0; i < 16; i++) u[i] = fmaxf(sc0[i], sc1[i]);
#pragma unroll
    for (int i = 0; i < 8; i++) u[i] = fmaxf(u[i], u[i + 8]);
#pragma unroll
    for (int i = 0; i < 4; i++) u[i] = fmaxf(u[i], u[i + 4]);
    float mx = fmaxf(fmaxf(u[0], u[1]), fmaxf(u[2], u[3]));
    mx = fmaxf(mx, __shfl_xor(mx, 32));

    // ---- T13 defer-max (rare path touches oacc + lacc) ----
    if (__any((mx - m) * CEXP > 8.0f)) {
      const float mn = fmaxf(m, mx);
      const float corr = exp2f((m - mn) * CEXP);
#pragma unroll
      for (int i = 0; i < 16; i++) lacc[i] *= corr;
#pragma unroll
      for (int dt = 0; dt < 4; dt++)
#pragma unroll
        for (int i = 0; i < 16; i++) oacc[dt][i] *= corr;
      m = mn;
    }

    // ---- exp + pack P -> frags (cvt_pk + permlane32_swap) ----
    const float mC = m * CEXP;
    float e0[16], e1[16];
#pragma unroll
    for (int i = 0; i < 16; i++) {
      e0[i] = exp2f(fmaf(sc0[i], CEXP, -mC));
      e1[i] = exp2f(fmaf(sc1[i], CEXP, -mC));
    }
    {
      uint32_t a, bw;
      u32x4 f;
      a = pkbf(e0[0], e0[1]);  bw = pkbf(e0[4], e0[5]);  swap32(a, bw);
      f[0] = a; f[2] = bw;
      a = pkbf(e0[2], e0[3]);  bw = pkbf(e0[6], e0[7]);  swap32(a, bw);
      f[1] = a; f[3] = bw;
      pf0 = __builtin_bit_cast(bf16x8, f);
      a = pkbf(e0[8], e0[9]);  bw = pkbf(e0[12], e0[13]); swap32(a, bw);
      f[0] = a; f[2] = bw;
      a = pkbf(e0[10], e0[11]); bw = pkbf(e0[14], e0[15]); swap32(a, bw);
      f[1] = a; f[3] = bw;
      pf1 = __builtin_bit_cast(bf16x8, f);
      a = pkbf(e1[0], e1[1]);  bw = pkbf(e1[4], e1[5]);  swap32(a, bw);
      f[0] = a; f[2] = bw;
      a = pkbf(e1[2], e1[3]);  bw = pkbf(e1[6], e1[7]);  swap32(a, bw);
      f[1] = a; f[3] = bw;
      pf2 = __builtin_bit_cast(bf16x8, f);
      a = pkbf(e1[8], e1[9]);  bw = pkbf(e1[12], e1[13]); swap32(a, bw);
      f[0] = a; f[2] = bw;
      a = pkbf(e1[10], e1[11]); bw = pkbf(e1[14], e1[15]); swap32(a, bw);
      f[1] = a; f[3] = bw;
      pf3 = __builtin_bit_cast(bf16x8, f);
    }

    // ---- row-sum via ones-MFMA into persistent lacc (replaces sum tree + shfl) ----
    lacc = MFMA32(ones, pf0, lacc);
    lacc = MFMA32(ones, pf1, lacc);
    lacc = MFMA32(ones, pf2, lacc);
    lacc = MFMA32(ones, pf3, lacc);

    if (sb < 31) writeV(vnext, v00, v01, v10, v11);  // write-late
    __syncthreads();

    const int tmp = vprev; vprev = vcur; vcur = vnext; vnext = tmp;
  }

  // ---- tail: PV(31) ----
  {
    __builtin_amdgcn_s_setprio(1);
#pragma unroll
    for (int dt = 0; dt < 4; dt++) {
      oacc[dt] = MFMA32(VFRAG(vprev, dt, 0), pf0, oacc[dt]);
      oacc[dt] = MFMA32(VFRAG(vprev, dt, 1), pf1, oacc[dt]);
      oacc[dt] = MFMA32(VFRAG(vprev, dt, 2), pf2, oacc[dt]);
      oacc[dt] = MFMA32(VFRAG(vprev, dt, 3), pf3, oacc[dt]);
    }
    __builtin_amdgcn_s_setprio(0);
  }
  __syncthreads();

  // ---- epilogue: normalize, per-wave LDS transpose, coalesced store ----
  // FIX: waves 2/3 use Vb[0]/Vb[1] bases (8192-u16 stride; region needs 4344 u16).
  const float rl = 1.0f / lacc[0];
  u16* ob = (w < 2) ? &Kb[w][0] : &Vb[w - 2][0][0];
#pragma unroll
  for (int dt = 0; dt < 4; dt++)
#pragma unroll
    for (int rq = 0; rq < 4; rq++) {
      u16x4 pv;
#pragma unroll
      for (int k = 0; k < 4; k++) pv[k] = f2bf(oacc[dt][rq * 4 + k] * rl);
      *reinterpret_cast<u16x4*>(&ob[lq * 136 + dt * 32 + rq * 8 + hi * 4]) = pv;
    }
  const int orow = lane >> 1, och = (lane & 1) * 64;
  u16* og = O + (rowb + qbase + orow) * 2048 + h * 128 + och;
#pragma unroll
  for (int t = 0; t < 8; t++) {
    u16x8 v = *reinterpret_cast<const u16x8*>(&ob[orow * 136 + och + t * 8]);
    *reinterpret_cast<u16x8*>(og + t * 8) = v;
  }
#undef KFRAG
#undef VFRAG
}

// ---------------- launch ----------------
extern "C" void kernel_launch(void* const* d_in, const int* in_sizes, int n_in,
                              void* d_out, int out_size, void* d_ws, size_t ws_size,
                              hipStream_t stream) {
  (void)in_sizes; (void)n_in; (void)out_size;
  const float* x  = (const float*)d_in[0];
  const float* Wq = (const float*)d_in[1];
  const float* Wk = (const float*)d_in[2];
  const float* Wv = (const float*)d_in[3];
  const float* Wo = (const float*)d_in[4];

  if (ws_size < (size_t)(8388608 + 6291456 + 12582912) * 2) return;
  u16* xb  = (u16*)d_ws;
  u16* Wc  = xb + 8388608;
  u16* QKV = Wc + 6291456;
  u16* Ob  = xb;  // reuse x-bf16 region for attention output

  cvt4_kernel<<<2048, 256, 0, stream>>>(x, Wq, Wk, Wv, xb, Wc);
  gemm_bt<true><<<dim3(24, 32), 256, 0, stream>>>(xb, Wc, (void*)QKV, 4096, 3072, 2048);
  cvt_kernel<<<2048, 256, 0, stream>>>(Wo, Wc, 1048576);
  attn_kernel<<<dim3(512), 256, 0, stream>>>(QKV, Ob);
  gemm_bt<false><<<dim3(16, 32), 256, 0, stream>>>(Ob, Wc, d_out, 4096, 2048, 2048);
}